// Round 3
// baseline (696.827 us; speedup 1.0000x reference)
//
#include <hip/hip_runtime.h>
#include <math.h>

// ---------------------------------------------------------------------------
// GCN: h1 = relu(norm_agg(x@W1)+b1); h2 = norm_agg(h1@W2)+b2;
//      g = mean_pool(h2, batch); out = relu(g@W3+b3)@W4 + b4
// norm_agg(h)[d] = (sum_{e: dst=d} h[src]*dinv[src] + h[d]*dinv[d]) * dinv[d]
// Strategy: CSR once; GEMM epilogue pre-scales rows by dinv[row]; aggregation
// gathers with 16 lanes/edge x 4 edges/instruction (float4), 16 edges in
// flight per wave; pooling fused into layer-2 aggregation.
// ---------------------------------------------------------------------------

__global__ __launch_bounds__(256) void k_zero(int* cnt, float* gsum, float* gcnt,
                                              int n, int gsz, int ng) {
  int i = blockIdx.x * 256 + threadIdx.x;
  if (i < n) cnt[i] = 0;
  if (i < gsz) gsum[i] = 0.f;
  if (i < ng) gcnt[i] = 0.f;
}

__global__ __launch_bounds__(256) void k_count(const int* __restrict__ dst,
                                               int* __restrict__ cnt, int e) {
  int i = blockIdx.x * 256 + threadIdx.x;
  if (i < e) atomicAdd(&cnt[dst[i]], 1);
}

// Exclusive scan, level A: each block scans a 1024-element chunk.
__global__ __launch_bounds__(256) void k_scanA(const int* __restrict__ cnt,
                                               int* __restrict__ startArr,
                                               int* __restrict__ bsum, int n) {
  __shared__ int sh[256];
  int t = threadIdx.x, b = blockIdx.x;
  int base = b * 1024 + t * 4;
  int v0 = 0, v1 = 0, v2 = 0, v3 = 0;
  if (base + 3 < n) {
    int4 v = *(const int4*)&cnt[base];
    v0 = v.x; v1 = v.y; v2 = v.z; v3 = v.w;
  } else {
    if (base + 0 < n) v0 = cnt[base + 0];
    if (base + 1 < n) v1 = cnt[base + 1];
    if (base + 2 < n) v2 = cnt[base + 2];
  }
  int local = v0 + v1 + v2 + v3;
  sh[t] = local;
  __syncthreads();
  for (int off = 1; off < 256; off <<= 1) {
    int x = (t >= off) ? sh[t - off] : 0;
    __syncthreads();
    sh[t] += x;
    __syncthreads();
  }
  int excl = sh[t] - local;
  if (t == 255) bsum[b] = sh[255];
  if (base + 0 < n) startArr[base + 0] = excl;
  if (base + 1 < n) startArr[base + 1] = excl + v0;
  if (base + 2 < n) startArr[base + 2] = excl + v0 + v1;
  if (base + 3 < n) startArr[base + 3] = excl + v0 + v1 + v2;
}

// Level B: single block scans the (<=256) chunk totals, in place, exclusive.
__global__ __launch_bounds__(256) void k_scanB(int* __restrict__ bsum, int nb) {
  __shared__ int sh[256];
  int t = threadIdx.x;
  int v = (t < nb) ? bsum[t] : 0;
  sh[t] = v;
  __syncthreads();
  for (int off = 1; off < 256; off <<= 1) {
    int x = (t >= off) ? sh[t - off] : 0;
    __syncthreads();
    sh[t] += x;
    __syncthreads();
  }
  if (t < nb) bsum[t] = sh[t] - v;
}

// Level C: add chunk offsets; init cursor; compute dinv = 1/sqrt(deg+1).
__global__ __launch_bounds__(256) void k_scanC(int* __restrict__ startArr,
                                               int* __restrict__ cursor,
                                               const int* __restrict__ bsum,
                                               const int* __restrict__ cnt,
                                               float* __restrict__ dinv, int n) {
  int i = blockIdx.x * 256 + threadIdx.x;
  if (i >= n) return;
  int s = startArr[i] + bsum[i >> 10];
  startArr[i] = s;
  cursor[i] = s;
  dinv[i] = 1.0f / sqrtf((float)(cnt[i] + 1));
}

__global__ __launch_bounds__(256) void k_place(const int* __restrict__ src,
                                               const int* __restrict__ dst,
                                               int* __restrict__ cursor,
                                               int* __restrict__ csr, int e) {
  int i = blockIdx.x * 256 + threadIdx.x;
  if (i >= e) return;
  int d = dst[i];
  int pos = atomicAdd(&cursor[d], 1);
  csr[pos] = src[i];
}

// Y[N,64] = (X[N,64] @ W[64,64]) * dinv[row]  (row-scaled epilogue).
__global__ __launch_bounds__(256) void k_gemm64s(const float* __restrict__ X,
                                                 const float* __restrict__ W,
                                                 const float* __restrict__ dinv,
                                                 float* __restrict__ Y, int n) {
  __shared__ float Xs[64 * 65];
  __shared__ float Ws[64 * 64];
  int t = threadIdx.x;
  int r0 = blockIdx.x << 6;
  for (int i = t * 4; i < 4096; i += 1024)
    *(float4*)&Ws[i] = *(const float4*)&W[i];
  for (int s = t; s < 1024; s += 256) {
    int r = s >> 4, c4 = (s & 15) << 2;
    float4 v = make_float4(0.f, 0.f, 0.f, 0.f);
    if (r0 + r < n) v = *(const float4*)&X[(size_t)(r0 + r) * 64 + c4];
    Xs[r * 65 + c4 + 0] = v.x;
    Xs[r * 65 + c4 + 1] = v.y;
    Xs[r * 65 + c4 + 2] = v.z;
    Xs[r * 65 + c4 + 3] = v.w;
  }
  __syncthreads();
  int c4 = (t & 15) << 2;
  int rb = (t >> 4) << 2;
  float4 a0 = {0, 0, 0, 0}, a1 = {0, 0, 0, 0}, a2 = {0, 0, 0, 0}, a3 = {0, 0, 0, 0};
  for (int k = 0; k < 64; ++k) {
    float4 w = *(const float4*)&Ws[k * 64 + c4];
    float x0 = Xs[(rb + 0) * 65 + k];
    float x1 = Xs[(rb + 1) * 65 + k];
    float x2 = Xs[(rb + 2) * 65 + k];
    float x3 = Xs[(rb + 3) * 65 + k];
    a0.x += x0 * w.x; a0.y += x0 * w.y; a0.z += x0 * w.z; a0.w += x0 * w.w;
    a1.x += x1 * w.x; a1.y += x1 * w.y; a1.z += x1 * w.z; a1.w += x1 * w.w;
    a2.x += x2 * w.x; a2.y += x2 * w.y; a2.z += x2 * w.z; a2.w += x2 * w.w;
    a3.x += x3 * w.x; a3.y += x3 * w.y; a3.z += x3 * w.z; a3.w += x3 * w.w;
  }
  int r = r0 + rb;
  if (r + 0 < n) {
    float s0 = dinv[r + 0];
    a0.x *= s0; a0.y *= s0; a0.z *= s0; a0.w *= s0;
    *(float4*)&Y[(size_t)(r + 0) * 64 + c4] = a0;
  }
  if (r + 1 < n) {
    float s1 = dinv[r + 1];
    a1.x *= s1; a1.y *= s1; a1.z *= s1; a1.w *= s1;
    *(float4*)&Y[(size_t)(r + 1) * 64 + c4] = a1;
  }
  if (r + 2 < n) {
    float s2 = dinv[r + 2];
    a2.x *= s2; a2.y *= s2; a2.z *= s2; a2.w *= s2;
    *(float4*)&Y[(size_t)(r + 2) * 64 + c4] = a2;
  }
  if (r + 3 < n) {
    float s3 = dinv[r + 3];
    a3.x *= s3; a3.y *= s3; a3.z *= s3; a3.w *= s3;
    *(float4*)&Y[(size_t)(r + 3) * 64 + c4] = a3;
  }
}

// Gather-sum of pre-scaled rows. 16 lanes per edge (float4 each), 4 edges per
// wave-instruction, unroll 4 -> 16 edges (4 KB) in flight per wave. Uniform
// fast path for full 16-edge chunks; group-masked tail (no wasted loads).
// Returns the cross-group-folded partial sum (all lanes hold the total).
__device__ __forceinline__ float4 gather4(const float* __restrict__ Hs,
                                          const int* __restrict__ csr,
                                          int p0, int p_end, int sub, int grp) {
  const float4* __restrict__ H4 = (const float4*)Hs;
  float4 acc = make_float4(0.f, 0.f, 0.f, 0.f);
  int p = p0;
  for (; p + 16 <= p_end; p += 16) {
#pragma unroll
    for (int j = 0; j < 4; ++j) {
      int s = csr[p + j * 4 + grp];
      float4 v = H4[(size_t)s * 16 + sub];
      acc.x += v.x; acc.y += v.y; acc.z += v.z; acc.w += v.w;
    }
  }
  if (p < p_end) {
#pragma unroll
    for (int j = 0; j < 4; ++j) {
      int q = p + j * 4 + grp;
      if (q < p_end) {
        int s = csr[q];
        float4 v = H4[(size_t)s * 16 + sub];
        acc.x += v.x; acc.y += v.y; acc.z += v.z; acc.w += v.w;
      }
    }
  }
  acc.x += __shfl_xor(acc.x, 16); acc.y += __shfl_xor(acc.y, 16);
  acc.z += __shfl_xor(acc.z, 16); acc.w += __shfl_xor(acc.w, 16);
  acc.x += __shfl_xor(acc.x, 32); acc.y += __shfl_xor(acc.y, 32);
  acc.z += __shfl_xor(acc.z, 32); acc.w += __shfl_xor(acc.w, 32);
  return acc;
}

// Layer-1 aggregation: one wave per node; out = relu(agg*dinv + b).
__global__ __launch_bounds__(256) void k_agg_relu(
    const float* __restrict__ Hs, const int* __restrict__ csr,
    const int* __restrict__ startArr, const int* __restrict__ cnt,
    const float* __restrict__ dinv, const float* __restrict__ bias,
    float* __restrict__ out, int n) {
  int wid = (blockIdx.x * 256 + threadIdx.x) >> 6;
  int lane = threadIdx.x & 63;
  if (wid >= n) return;
  int sub = lane & 15, grp = lane >> 4;
  int p0 = startArr[wid];
  int c = cnt[wid];
  float dn = dinv[wid];
  float4 acc = gather4(Hs, csr, p0, p0 + c, sub, grp);
  float4 self = ((const float4*)Hs)[(size_t)wid * 16 + sub];
  float4 bb = ((const float4*)bias)[sub];
  float4 r;
  r.x = fmaxf((acc.x + self.x) * dn + bb.x, 0.f);
  r.y = fmaxf((acc.y + self.y) * dn + bb.y, 0.f);
  r.z = fmaxf((acc.z + self.z) * dn + bb.z, 0.f);
  r.w = fmaxf((acc.w + self.w) * dn + bb.w, 0.f);
  if (grp == 0) ((float4*)out)[(size_t)wid * 16 + sub] = r;
}

// Layer-2 aggregation fused with mean-pool accumulation.
__global__ __launch_bounds__(256) void k_agg_pool(
    const float* __restrict__ Hs, const int* __restrict__ csr,
    const int* __restrict__ startArr, const int* __restrict__ cnt,
    const float* __restrict__ dinv, const float* __restrict__ bias,
    const int* __restrict__ batch, float* __restrict__ gsum,
    float* __restrict__ gcnt, int n) {
  int wid = (blockIdx.x * 256 + threadIdx.x) >> 6;
  int lane = threadIdx.x & 63;
  if (wid >= n) return;
  int sub = lane & 15, grp = lane >> 6 ? 0 : (lane >> 4);
  grp = lane >> 4;
  int p0 = startArr[wid];
  int c = cnt[wid];
  float dn = dinv[wid];
  float4 acc = gather4(Hs, csr, p0, p0 + c, sub, grp);
  float4 self = ((const float4*)Hs)[(size_t)wid * 16 + sub];
  float4 bb = ((const float4*)bias)[sub];
  float4 r;
  r.x = (acc.x + self.x) * dn + bb.x;
  r.y = (acc.y + self.y) * dn + bb.y;
  r.z = (acc.z + self.z) * dn + bb.z;
  r.w = (acc.w + self.w) * dn + bb.w;
  int g = batch[wid];
  if (grp == 0) {
    float* gp = &gsum[(size_t)g * 64 + sub * 4];
    atomicAdd(gp + 0, r.x);
    atomicAdd(gp + 1, r.y);
    atomicAdd(gp + 2, r.z);
    atomicAdd(gp + 3, r.w);
  }
  if (lane == 0) atomicAdd(&gcnt[g], 1.0f);
}

// Head: per-graph wave: m = gsum/max(cnt,1); t = relu(m@W3+b3); out = t.W4+b4
__global__ __launch_bounds__(256) void k_head(
    const float* __restrict__ gsum, const float* __restrict__ gcnt,
    const float* __restrict__ W3, const float* __restrict__ b3,
    const float* __restrict__ W4, const float* __restrict__ b4,
    float* __restrict__ out, int ng) {
  int wid = (blockIdx.x * 256 + threadIdx.x) >> 6;
  int lane = threadIdx.x & 63;
  if (wid >= ng) return;
  float cden = fmaxf(gcnt[wid], 1.0f);
  float m = gsum[(size_t)wid * 64 + lane] / cden;
  float acc = b3[lane];
  for (int k = 0; k < 64; ++k) {
    float mk = __shfl(m, k);
    acc += mk * W3[k * 64 + lane];
  }
  acc = fmaxf(acc, 0.f);
  float r = acc * W4[lane];
  for (int off = 32; off; off >>= 1) r += __shfl_down(r, off);
  if (lane == 0) out[wid] = r + b4[0];
}

extern "C" void kernel_launch(void* const* d_in, const int* in_sizes, int n_in,
                              void* d_out, int out_size, void* d_ws, size_t ws_size,
                              hipStream_t stream) {
  const float* x = (const float*)d_in[0];
  const int* edge = (const int*)d_in[1];   // [2, E] int32
  const int* batch = (const int*)d_in[2];  // [N] int32, sorted
  const float* W1 = (const float*)d_in[3];
  const float* b1 = (const float*)d_in[4];
  const float* W2 = (const float*)d_in[5];
  const float* b2 = (const float*)d_in[6];
  const float* W3 = (const float*)d_in[7];
  const float* b3 = (const float*)d_in[8];
  const float* W4 = (const float*)d_in[9];
  const float* b4 = (const float*)d_in[10];
  float* out = (float*)d_out;

  const int n = in_sizes[0] / 64;   // 100000
  const int e = in_sizes[1] / 2;    // 1600000
  const int ng = out_size;          // 512
  const int* src = edge;
  const int* dst = edge + e;

  // Workspace layout (~59.4 MB total).
  char* ws = (char*)d_ws;
  size_t off = 0;
  auto alloc = [&](size_t bytes) -> void* {
    void* p = ws + off;
    off = (off + bytes + 255) & ~(size_t)255;
    return p;
  };
  float* A = (float*)alloc((size_t)n * 64 * 4);      // Hs (scaled gemm output)
  float* B = (float*)alloc((size_t)n * 64 * 4);      // aggregated / relu
  float* dinv = (float*)alloc((size_t)n * 4);
  int* cnt = (int*)alloc((size_t)n * 4);
  int* startArr = (int*)alloc((size_t)n * 4);
  int* cursor = (int*)alloc((size_t)n * 4);
  int* bsum = (int*)alloc(1024);
  int* csr = (int*)alloc((size_t)e * 4);
  float* gsum = (float*)alloc((size_t)ng * 64 * 4);
  float* gcnt = (float*)alloc((size_t)ng * 4);

  const int nb = (n + 1023) / 1024;  // scan chunks (98)

  int zmax = n;
  if (ng * 64 > zmax) zmax = ng * 64;
  k_zero<<<(zmax + 255) / 256, 256, 0, stream>>>(cnt, gsum, gcnt, n, ng * 64, ng);
  k_count<<<(e + 255) / 256, 256, 0, stream>>>(dst, cnt, e);
  k_scanA<<<nb, 256, 0, stream>>>(cnt, startArr, bsum, n);
  k_scanB<<<1, 256, 0, stream>>>(bsum, nb);
  k_scanC<<<(n + 255) / 256, 256, 0, stream>>>(startArr, cursor, bsum, cnt, dinv, n);
  k_place<<<(e + 255) / 256, 256, 0, stream>>>(src, dst, cursor, csr, e);

  // Layer 1: A = (x@W1)*dinv ; B = relu(agg(A)*dinv + b1)
  k_gemm64s<<<(n + 63) / 64, 256, 0, stream>>>(x, W1, dinv, A, n);
  k_agg_relu<<<((size_t)n * 64 + 255) / 256, 256, 0, stream>>>(A, csr, startArr, cnt,
                                                               dinv, b1, B, n);
  // Layer 2: A = (B@W2)*dinv ; pool(agg(A)*dinv + b2)
  k_gemm64s<<<(n + 63) / 64, 256, 0, stream>>>(B, W2, dinv, A, n);
  k_agg_pool<<<((size_t)n * 64 + 255) / 256, 256, 0, stream>>>(A, csr, startArr, cnt,
                                                               dinv, b2, batch, gsum,
                                                               gcnt, n);
  // Head
  k_head<<<((size_t)ng * 64 + 255) / 256, 256, 0, stream>>>(gsum, gcnt, W3, b3, W4,
                                                            b4, out, ng);
}

// Round 4
// 648.069 us; speedup vs baseline: 1.0752x; 1.0752x over previous
//
#include <hip/hip_runtime.h>
#include <math.h>

// ---------------------------------------------------------------------------
// GCN: h1 = relu(norm_agg(x@W1)+b1); h2 = norm_agg(h1@W2)+b2;
//      g = mean_pool(h2, batch); out = relu(g@W3+b3)@W4 + b4
// norm_agg(h)[d] = (sum_{e: dst=d} h[src]*dinv[src] + h[d]*dinv[d]) * dinv[d]
// Strategy: CSR once; GEMM epilogue pre-scales rows by dinv[row]; aggregation
// is a two-phase gather: 1 coalesced 16-index load -> readlane to SGPRs ->
// 16 row-gathers in flight (SGPR base + lane offset) -> one wait -> masked
// sum. Pooling fused into layer-2 agg with coalesced 64-lane atomics.
// ---------------------------------------------------------------------------

__global__ __launch_bounds__(256) void k_zero(int* cnt, float* gsum, float* gcnt,
                                              int n, int gsz, int ng) {
  int i = blockIdx.x * 256 + threadIdx.x;
  if (i < n) cnt[i] = 0;
  if (i < gsz) gsum[i] = 0.f;
  if (i < ng) gcnt[i] = 0.f;
}

__global__ __launch_bounds__(256) void k_count(const int* __restrict__ dst,
                                               int* __restrict__ cnt, int e) {
  int i = blockIdx.x * 256 + threadIdx.x;
  if (i < e) atomicAdd(&cnt[dst[i]], 1);
}

// Exclusive scan, level A: each block scans a 1024-element chunk.
__global__ __launch_bounds__(256) void k_scanA(const int* __restrict__ cnt,
                                               int* __restrict__ startArr,
                                               int* __restrict__ bsum, int n) {
  __shared__ int sh[256];
  int t = threadIdx.x, b = blockIdx.x;
  int base = b * 1024 + t * 4;
  int v0 = 0, v1 = 0, v2 = 0, v3 = 0;
  if (base + 3 < n) {
    int4 v = *(const int4*)&cnt[base];
    v0 = v.x; v1 = v.y; v2 = v.z; v3 = v.w;
  } else {
    if (base + 0 < n) v0 = cnt[base + 0];
    if (base + 1 < n) v1 = cnt[base + 1];
    if (base + 2 < n) v2 = cnt[base + 2];
  }
  int local = v0 + v1 + v2 + v3;
  sh[t] = local;
  __syncthreads();
  for (int off = 1; off < 256; off <<= 1) {
    int x = (t >= off) ? sh[t - off] : 0;
    __syncthreads();
    sh[t] += x;
    __syncthreads();
  }
  int excl = sh[t] - local;
  if (t == 255) bsum[b] = sh[255];
  if (base + 0 < n) startArr[base + 0] = excl;
  if (base + 1 < n) startArr[base + 1] = excl + v0;
  if (base + 2 < n) startArr[base + 2] = excl + v0 + v1;
  if (base + 3 < n) startArr[base + 3] = excl + v0 + v1 + v2;
}

// Level B: single block scans the (<=256) chunk totals, in place, exclusive.
__global__ __launch_bounds__(256) void k_scanB(int* __restrict__ bsum, int nb) {
  __shared__ int sh[256];
  int t = threadIdx.x;
  int v = (t < nb) ? bsum[t] : 0;
  sh[t] = v;
  __syncthreads();
  for (int off = 1; off < 256; off <<= 1) {
    int x = (t >= off) ? sh[t - off] : 0;
    __syncthreads();
    sh[t] += x;
    __syncthreads();
  }
  if (t < nb) bsum[t] = sh[t] - v;
}

// Level C: add chunk offsets; init cursor; compute dinv = 1/sqrt(deg+1).
__global__ __launch_bounds__(256) void k_scanC(int* __restrict__ startArr,
                                               int* __restrict__ cursor,
                                               const int* __restrict__ bsum,
                                               const int* __restrict__ cnt,
                                               float* __restrict__ dinv, int n) {
  int i = blockIdx.x * 256 + threadIdx.x;
  if (i >= n) return;
  int s = startArr[i] + bsum[i >> 10];
  startArr[i] = s;
  cursor[i] = s;
  dinv[i] = 1.0f / sqrtf((float)(cnt[i] + 1));
}

__global__ __launch_bounds__(256) void k_place(const int* __restrict__ src,
                                               const int* __restrict__ dst,
                                               int* __restrict__ cursor,
                                               int* __restrict__ csr, int e) {
  int i = blockIdx.x * 256 + threadIdx.x;
  if (i >= e) return;
  int d = dst[i];
  int pos = atomicAdd(&cursor[d], 1);
  csr[pos] = src[i];
}

// Y[N,64] = (X[N,64] @ W[64,64]) * dinv[row]  (row-scaled epilogue).
__global__ __launch_bounds__(256) void k_gemm64s(const float* __restrict__ X,
                                                 const float* __restrict__ W,
                                                 const float* __restrict__ dinv,
                                                 float* __restrict__ Y, int n) {
  __shared__ float Xs[64 * 65];
  __shared__ float Ws[64 * 64];
  int t = threadIdx.x;
  int r0 = blockIdx.x << 6;
  for (int i = t * 4; i < 4096; i += 1024)
    *(float4*)&Ws[i] = *(const float4*)&W[i];
  for (int s = t; s < 1024; s += 256) {
    int r = s >> 4, c4 = (s & 15) << 2;
    float4 v = make_float4(0.f, 0.f, 0.f, 0.f);
    if (r0 + r < n) v = *(const float4*)&X[(size_t)(r0 + r) * 64 + c4];
    Xs[r * 65 + c4 + 0] = v.x;
    Xs[r * 65 + c4 + 1] = v.y;
    Xs[r * 65 + c4 + 2] = v.z;
    Xs[r * 65 + c4 + 3] = v.w;
  }
  __syncthreads();
  int c4 = (t & 15) << 2;
  int rb = (t >> 4) << 2;
  float4 a0 = {0, 0, 0, 0}, a1 = {0, 0, 0, 0}, a2 = {0, 0, 0, 0}, a3 = {0, 0, 0, 0};
  for (int k = 0; k < 64; ++k) {
    float4 w = *(const float4*)&Ws[k * 64 + c4];
    float x0 = Xs[(rb + 0) * 65 + k];
    float x1 = Xs[(rb + 1) * 65 + k];
    float x2 = Xs[(rb + 2) * 65 + k];
    float x3 = Xs[(rb + 3) * 65 + k];
    a0.x += x0 * w.x; a0.y += x0 * w.y; a0.z += x0 * w.z; a0.w += x0 * w.w;
    a1.x += x1 * w.x; a1.y += x1 * w.y; a1.z += x1 * w.z; a1.w += x1 * w.w;
    a2.x += x2 * w.x; a2.y += x2 * w.y; a2.z += x2 * w.z; a2.w += x2 * w.w;
    a3.x += x3 * w.x; a3.y += x3 * w.y; a3.z += x3 * w.z; a3.w += x3 * w.w;
  }
  int r = r0 + rb;
  if (r + 0 < n) {
    float s0 = dinv[r + 0];
    a0.x *= s0; a0.y *= s0; a0.z *= s0; a0.w *= s0;
    *(float4*)&Y[(size_t)(r + 0) * 64 + c4] = a0;
  }
  if (r + 1 < n) {
    float s1 = dinv[r + 1];
    a1.x *= s1; a1.y *= s1; a1.z *= s1; a1.w *= s1;
    *(float4*)&Y[(size_t)(r + 1) * 64 + c4] = a1;
  }
  if (r + 2 < n) {
    float s2 = dinv[r + 2];
    a2.x *= s2; a2.y *= s2; a2.z *= s2; a2.w *= s2;
    *(float4*)&Y[(size_t)(r + 2) * 64 + c4] = a2;
  }
  if (r + 3 < n) {
    float s3 = dinv[r + 3];
    a3.x *= s3; a3.y *= s3; a3.z *= s3; a3.w *= s3;
    *(float4*)&Y[(size_t)(r + 3) * 64 + c4] = a3;
  }
}

// Two-phase gather-sum: per round of 16 edges, one coalesced clamped index
// load -> 16 readlanes (SGPR) -> up to 16 row gathers issued back-to-back
// (group-guarded by wave-uniform branches, no uses in between) -> one wait
// -> masked pairwise sum. ~16 x 256 B in flight per wave.
__device__ __forceinline__ float agg_gather(const float* __restrict__ Hs,
                                            const int* __restrict__ csr,
                                            int p0, int c, int lane) {
  float acc = 0.f;
  int sub = lane & 15;
  int qlast = p0 + c - 1;
  for (int rb = 0; rb < c; rb += 16) {
    int q = p0 + rb + sub;
    int idxv = csr[q < qlast ? q : qlast];  // clamped 16-wide coalesced
    int rem = c - rb;                       // wave-uniform
    int s0 = __builtin_amdgcn_readlane(idxv, 0);
    int s1 = __builtin_amdgcn_readlane(idxv, 1);
    int s2 = __builtin_amdgcn_readlane(idxv, 2);
    int s3 = __builtin_amdgcn_readlane(idxv, 3);
    int s4 = __builtin_amdgcn_readlane(idxv, 4);
    int s5 = __builtin_amdgcn_readlane(idxv, 5);
    int s6 = __builtin_amdgcn_readlane(idxv, 6);
    int s7 = __builtin_amdgcn_readlane(idxv, 7);
    int s8 = __builtin_amdgcn_readlane(idxv, 8);
    int s9 = __builtin_amdgcn_readlane(idxv, 9);
    int s10 = __builtin_amdgcn_readlane(idxv, 10);
    int s11 = __builtin_amdgcn_readlane(idxv, 11);
    int s12 = __builtin_amdgcn_readlane(idxv, 12);
    int s13 = __builtin_amdgcn_readlane(idxv, 13);
    int s14 = __builtin_amdgcn_readlane(idxv, 14);
    int s15 = __builtin_amdgcn_readlane(idxv, 15);
    float t0 = 0.f, t1 = 0.f, t2 = 0.f, t3 = 0.f;
    float t4 = 0.f, t5 = 0.f, t6 = 0.f, t7 = 0.f;
    float t8 = 0.f, t9 = 0.f, t10 = 0.f, t11 = 0.f;
    float t12 = 0.f, t13 = 0.f, t14 = 0.f, t15 = 0.f;
    {  // group 0 always present (rem >= 1)
      t0 = Hs[(size_t)s0 * 64 + lane];
      t1 = Hs[(size_t)s1 * 64 + lane];
      t2 = Hs[(size_t)s2 * 64 + lane];
      t3 = Hs[(size_t)s3 * 64 + lane];
    }
    if (rem > 4) {
      t4 = Hs[(size_t)s4 * 64 + lane];
      t5 = Hs[(size_t)s5 * 64 + lane];
      t6 = Hs[(size_t)s6 * 64 + lane];
      t7 = Hs[(size_t)s7 * 64 + lane];
    }
    if (rem > 8) {
      t8 = Hs[(size_t)s8 * 64 + lane];
      t9 = Hs[(size_t)s9 * 64 + lane];
      t10 = Hs[(size_t)s10 * 64 + lane];
      t11 = Hs[(size_t)s11 * 64 + lane];
    }
    if (rem > 12) {
      t12 = Hs[(size_t)s12 * 64 + lane];
      t13 = Hs[(size_t)s13 * 64 + lane];
      t14 = Hs[(size_t)s14 * 64 + lane];
      t15 = Hs[(size_t)s15 * 64 + lane];
    }
    // masked sum (clamped duplicates zeroed); one wait point for all gathers
    float a01 = t0 + ((1 < rem) ? t1 : 0.f);
    float a23 = ((2 < rem) ? t2 : 0.f) + ((3 < rem) ? t3 : 0.f);
    float a45 = ((4 < rem) ? t4 : 0.f) + ((5 < rem) ? t5 : 0.f);
    float a67 = ((6 < rem) ? t6 : 0.f) + ((7 < rem) ? t7 : 0.f);
    float a89 = ((8 < rem) ? t8 : 0.f) + ((9 < rem) ? t9 : 0.f);
    float aab = ((10 < rem) ? t10 : 0.f) + ((11 < rem) ? t11 : 0.f);
    float acd = ((12 < rem) ? t12 : 0.f) + ((13 < rem) ? t13 : 0.f);
    float aef = ((14 < rem) ? t14 : 0.f) + ((15 < rem) ? t15 : 0.f);
    acc += ((a01 + a23) + (a45 + a67)) + ((a89 + aab) + (acd + aef));
  }
  return acc;
}

// Layer-1 aggregation: one wave per node; out = relu(agg*dinv + b).
__global__ __launch_bounds__(256) void k_agg_relu(
    const float* __restrict__ Hs, const int* __restrict__ csr,
    const int* __restrict__ startArr, const int* __restrict__ cnt,
    const float* __restrict__ dinv, const float* __restrict__ bias,
    float* __restrict__ out, int n) {
  int wid = (blockIdx.x * 256 + threadIdx.x) >> 6;
  int lane = threadIdx.x & 63;
  if (wid >= n) return;
  float acc = agg_gather(Hs, csr, startArr[wid], cnt[wid], lane);
  acc += Hs[(size_t)wid * 64 + lane];  // self loop (pre-scaled)
  acc = acc * dinv[wid] + bias[lane];
  out[(size_t)wid * 64 + lane] = fmaxf(acc, 0.f);
}

// Layer-2 aggregation fused with mean-pool accumulation (coalesced atomics).
__global__ __launch_bounds__(256) void k_agg_pool(
    const float* __restrict__ Hs, const int* __restrict__ csr,
    const int* __restrict__ startArr, const int* __restrict__ cnt,
    const float* __restrict__ dinv, const float* __restrict__ bias,
    const int* __restrict__ batch, float* __restrict__ gsum,
    float* __restrict__ gcnt, int n) {
  int wid = (blockIdx.x * 256 + threadIdx.x) >> 6;
  int lane = threadIdx.x & 63;
  if (wid >= n) return;
  float acc = agg_gather(Hs, csr, startArr[wid], cnt[wid], lane);
  acc += Hs[(size_t)wid * 64 + lane];
  acc = acc * dinv[wid] + bias[lane];
  int g = batch[wid];
  atomicAdd(&gsum[(size_t)g * 64 + lane], acc);
  if (lane == 0) atomicAdd(&gcnt[g], 1.0f);
}

// Head: per-graph wave: m = gsum/max(cnt,1); t = relu(m@W3+b3); out = t.W4+b4
__global__ __launch_bounds__(256) void k_head(
    const float* __restrict__ gsum, const float* __restrict__ gcnt,
    const float* __restrict__ W3, const float* __restrict__ b3,
    const float* __restrict__ W4, const float* __restrict__ b4,
    float* __restrict__ out, int ng) {
  int wid = (blockIdx.x * 256 + threadIdx.x) >> 6;
  int lane = threadIdx.x & 63;
  if (wid >= ng) return;
  float cden = fmaxf(gcnt[wid], 1.0f);
  float m = gsum[(size_t)wid * 64 + lane] / cden;
  float acc = b3[lane];
  for (int k = 0; k < 64; ++k) {
    float mk = __shfl(m, k);
    acc += mk * W3[k * 64 + lane];
  }
  acc = fmaxf(acc, 0.f);
  float r = acc * W4[lane];
  for (int off = 32; off; off >>= 1) r += __shfl_down(r, off);
  if (lane == 0) out[wid] = r + b4[0];
}

extern "C" void kernel_launch(void* const* d_in, const int* in_sizes, int n_in,
                              void* d_out, int out_size, void* d_ws, size_t ws_size,
                              hipStream_t stream) {
  const float* x = (const float*)d_in[0];
  const int* edge = (const int*)d_in[1];   // [2, E] int32
  const int* batch = (const int*)d_in[2];  // [N] int32, sorted
  const float* W1 = (const float*)d_in[3];
  const float* b1 = (const float*)d_in[4];
  const float* W2 = (const float*)d_in[5];
  const float* b2 = (const float*)d_in[6];
  const float* W3 = (const float*)d_in[7];
  const float* b3 = (const float*)d_in[8];
  const float* W4 = (const float*)d_in[9];
  const float* b4 = (const float*)d_in[10];
  float* out = (float*)d_out;

  const int n = in_sizes[0] / 64;   // 100000
  const int e = in_sizes[1] / 2;    // 1600000
  const int ng = out_size;          // 512
  const int* src = edge;
  const int* dst = edge + e;

  // Workspace layout (~59.4 MB total).
  char* ws = (char*)d_ws;
  size_t off = 0;
  auto alloc = [&](size_t bytes) -> void* {
    void* p = ws + off;
    off = (off + bytes + 255) & ~(size_t)255;
    return p;
  };
  float* A = (float*)alloc((size_t)n * 64 * 4);      // Hs (scaled gemm output)
  float* B = (float*)alloc((size_t)n * 64 * 4);      // aggregated / relu
  float* dinv = (float*)alloc((size_t)n * 4);
  int* cnt = (int*)alloc((size_t)n * 4);
  int* startArr = (int*)alloc((size_t)n * 4);
  int* cursor = (int*)alloc((size_t)n * 4);
  int* bsum = (int*)alloc(1024);
  int* csr = (int*)alloc((size_t)e * 4);
  float* gsum = (float*)alloc((size_t)ng * 64 * 4);
  float* gcnt = (float*)alloc((size_t)ng * 4);

  const int nb = (n + 1023) / 1024;  // scan chunks (98)

  int zmax = n;
  if (ng * 64 > zmax) zmax = ng * 64;
  k_zero<<<(zmax + 255) / 256, 256, 0, stream>>>(cnt, gsum, gcnt, n, ng * 64, ng);
  k_count<<<(e + 255) / 256, 256, 0, stream>>>(dst, cnt, e);
  k_scanA<<<nb, 256, 0, stream>>>(cnt, startArr, bsum, n);
  k_scanB<<<1, 256, 0, stream>>>(bsum, nb);
  k_scanC<<<(n + 255) / 256, 256, 0, stream>>>(startArr, cursor, bsum, cnt, dinv, n);
  k_place<<<(e + 255) / 256, 256, 0, stream>>>(src, dst, cursor, csr, e);

  // Layer 1: A = (x@W1)*dinv ; B = relu(agg(A)*dinv + b1)
  k_gemm64s<<<(n + 63) / 64, 256, 0, stream>>>(x, W1, dinv, A, n);
  k_agg_relu<<<((size_t)n * 64 + 255) / 256, 256, 0, stream>>>(A, csr, startArr, cnt,
                                                               dinv, b1, B, n);
  // Layer 2: A = (B@W2)*dinv ; pool(agg(A)*dinv + b2)
  k_gemm64s<<<(n + 63) / 64, 256, 0, stream>>>(B, W2, dinv, A, n);
  k_agg_pool<<<((size_t)n * 64 + 255) / 256, 256, 0, stream>>>(A, csr, startArr, cnt,
                                                               dinv, b2, batch, gsum,
                                                               gcnt, n);
  // Head
  k_head<<<((size_t)ng * 64 + 255) / 256, 256, 0, stream>>>(gsum, gcnt, W3, b3, W4,
                                                            b4, out, ng);
}

// Round 5
// 593.441 us; speedup vs baseline: 1.1742x; 1.0921x over previous
//
#include <hip/hip_runtime.h>
#include <math.h>

// ---------------------------------------------------------------------------
// GCN: h1 = relu(norm_agg(x@W1)+b1); h2 = norm_agg(h1@W2)+b2;
//      g = mean_pool(h2, batch); out = relu(g@W3+b3)@W4 + b4
// norm_agg(h)[d] = (sum_{e: dst=d} h[src]*dinv[src] + h[d]*dinv[d]) * dinv[d]
// Strategy: CSR once; GEMM epilogue pre-scales rows by dinv[row].
// Aggregation: wave owns 32 consecutive dsts (LDS accumulators); its edge
// segment is packed (src<<5|dst_local) and counting-sorted by src so all
// waves sweep src-space in the same order -> collective read front is
// L2-resident and HBM refill is sequential (vs random 256B, the R2-R4 cap).
// ---------------------------------------------------------------------------

__global__ __launch_bounds__(256) void k_zero(int* cnt, float* gsum, float* gcnt,
                                              int n, int gsz, int ng) {
  int i = blockIdx.x * 256 + threadIdx.x;
  if (i < n) cnt[i] = 0;
  if (i < gsz) gsum[i] = 0.f;
  if (i < ng) gcnt[i] = 0.f;
}

__global__ __launch_bounds__(256) void k_count(const int* __restrict__ dst,
                                               int* __restrict__ cnt, int e) {
  int i = blockIdx.x * 256 + threadIdx.x;
  if (i < e) atomicAdd(&cnt[dst[i]], 1);
}

// Exclusive scan, level A: each block scans a 1024-element chunk.
__global__ __launch_bounds__(256) void k_scanA(const int* __restrict__ cnt,
                                               int* __restrict__ startArr,
                                               int* __restrict__ bsum, int n) {
  __shared__ int sh[256];
  int t = threadIdx.x, b = blockIdx.x;
  int base = b * 1024 + t * 4;
  int v0 = 0, v1 = 0, v2 = 0, v3 = 0;
  if (base + 3 < n) {
    int4 v = *(const int4*)&cnt[base];
    v0 = v.x; v1 = v.y; v2 = v.z; v3 = v.w;
  } else {
    if (base + 0 < n) v0 = cnt[base + 0];
    if (base + 1 < n) v1 = cnt[base + 1];
    if (base + 2 < n) v2 = cnt[base + 2];
  }
  int local = v0 + v1 + v2 + v3;
  sh[t] = local;
  __syncthreads();
  for (int off = 1; off < 256; off <<= 1) {
    int x = (t >= off) ? sh[t - off] : 0;
    __syncthreads();
    sh[t] += x;
    __syncthreads();
  }
  int excl = sh[t] - local;
  if (t == 255) bsum[b] = sh[255];
  if (base + 0 < n) startArr[base + 0] = excl;
  if (base + 1 < n) startArr[base + 1] = excl + v0;
  if (base + 2 < n) startArr[base + 2] = excl + v0 + v1;
  if (base + 3 < n) startArr[base + 3] = excl + v0 + v1 + v2;
}

// Level B: single block scans the (<=256) chunk totals, in place, exclusive.
__global__ __launch_bounds__(256) void k_scanB(int* __restrict__ bsum, int nb) {
  __shared__ int sh[256];
  int t = threadIdx.x;
  int v = (t < nb) ? bsum[t] : 0;
  sh[t] = v;
  __syncthreads();
  for (int off = 1; off < 256; off <<= 1) {
    int x = (t >= off) ? sh[t - off] : 0;
    __syncthreads();
    sh[t] += x;
    __syncthreads();
  }
  if (t < nb) bsum[t] = sh[t] - v;
}

// Level C: add chunk offsets; init cursor; dinv = 1/sqrt(deg+1); gcnt.
__global__ __launch_bounds__(256) void k_scanC(int* __restrict__ startArr,
                                               int* __restrict__ cursor,
                                               const int* __restrict__ bsum,
                                               const int* __restrict__ cnt,
                                               float* __restrict__ dinv,
                                               const int* __restrict__ batch,
                                               float* __restrict__ gcnt, int n) {
  int i = blockIdx.x * 256 + threadIdx.x;
  if (i >= n) return;
  int s = startArr[i] + bsum[i >> 10];
  startArr[i] = s;
  cursor[i] = s;
  dinv[i] = 1.0f / sqrtf((float)(cnt[i] + 1));
  atomicAdd(&gcnt[batch[i]], 1.0f);
}

// Place packed entries (src<<5 | dst&31) into per-node CSR slots.
__global__ __launch_bounds__(256) void k_place(const int* __restrict__ src,
                                               const int* __restrict__ dst,
                                               int* __restrict__ cursor,
                                               int* __restrict__ csr, int e) {
  int i = blockIdx.x * 256 + threadIdx.x;
  if (i >= e) return;
  int d = dst[i];
  int pos = atomicAdd(&cursor[d], 1);
  csr[pos] = (src[i] << 5) | (d & 31);
}

// Per-node-block (32 dsts) counting sort of the packed edge segment by
// src>>11 (64 bins of 2048 rows). Locality-only transform: skipping it (seg
// too big / empty) leaves results correct.
__global__ __launch_bounds__(256) void k_bsort(const int* __restrict__ startArr,
                                               int* __restrict__ csr, int n, int e) {
  __shared__ int in_sh[1024];
  __shared__ int out_sh[1024];
  __shared__ int hist[64];
  __shared__ int hscan[64];
  int nodeBase = blockIdx.x << 5;
  if (nodeBase >= n) return;
  int p0 = startArr[nodeBase];
  int p1 = (nodeBase + 32 < n) ? startArr[nodeBase + 32] : e;
  int seg = p1 - p0;
  if (seg <= 0 || seg > 1024) return;  // block-uniform exit
  int t = threadIdx.x;
  if (t < 64) hist[t] = 0;
  __syncthreads();
  for (int i = t; i < seg; i += 256) {
    int v = csr[p0 + i];
    in_sh[i] = v;
    atomicAdd(&hist[v >> 16], 1);  // (src<<5)>>16 == src>>11
  }
  __syncthreads();
  if (t == 0) {
    int s = 0;
    for (int b = 0; b < 64; ++b) {
      hscan[b] = s;
      s += hist[b];
    }
  }
  __syncthreads();
  for (int i = t; i < seg; i += 256) {
    int v = in_sh[i];
    int pos = atomicAdd(&hscan[v >> 16], 1);
    out_sh[pos] = v;
  }
  __syncthreads();
  for (int i = t; i < seg; i += 256) csr[p0 + i] = out_sh[i];
}

// Y[N,64] = (X[N,64] @ W[64,64]) * dinv[row]  (row-scaled epilogue).
__global__ __launch_bounds__(256) void k_gemm64s(const float* __restrict__ X,
                                                 const float* __restrict__ W,
                                                 const float* __restrict__ dinv,
                                                 float* __restrict__ Y, int n) {
  __shared__ float Xs[64 * 65];
  __shared__ float Ws[64 * 64];
  int t = threadIdx.x;
  int r0 = blockIdx.x << 6;
  for (int i = t * 4; i < 4096; i += 1024)
    *(float4*)&Ws[i] = *(const float4*)&W[i];
  for (int s = t; s < 1024; s += 256) {
    int r = s >> 4, c4 = (s & 15) << 2;
    float4 v = make_float4(0.f, 0.f, 0.f, 0.f);
    if (r0 + r < n) v = *(const float4*)&X[(size_t)(r0 + r) * 64 + c4];
    Xs[r * 65 + c4 + 0] = v.x;
    Xs[r * 65 + c4 + 1] = v.y;
    Xs[r * 65 + c4 + 2] = v.z;
    Xs[r * 65 + c4 + 3] = v.w;
  }
  __syncthreads();
  int c4 = (t & 15) << 2;
  int rb = (t >> 4) << 2;
  float4 a0 = {0, 0, 0, 0}, a1 = {0, 0, 0, 0}, a2 = {0, 0, 0, 0}, a3 = {0, 0, 0, 0};
  for (int k = 0; k < 64; ++k) {
    float4 w = *(const float4*)&Ws[k * 64 + c4];
    float x0 = Xs[(rb + 0) * 65 + k];
    float x1 = Xs[(rb + 1) * 65 + k];
    float x2 = Xs[(rb + 2) * 65 + k];
    float x3 = Xs[(rb + 3) * 65 + k];
    a0.x += x0 * w.x; a0.y += x0 * w.y; a0.z += x0 * w.z; a0.w += x0 * w.w;
    a1.x += x1 * w.x; a1.y += x1 * w.y; a1.z += x1 * w.z; a1.w += x1 * w.w;
    a2.x += x2 * w.x; a2.y += x2 * w.y; a2.z += x2 * w.z; a2.w += x2 * w.w;
    a3.x += x3 * w.x; a3.y += x3 * w.y; a3.z += x3 * w.z; a3.w += x3 * w.w;
  }
  int r = r0 + rb;
  if (r + 0 < n) {
    float s0 = dinv[r + 0];
    a0.x *= s0; a0.y *= s0; a0.z *= s0; a0.w *= s0;
    *(float4*)&Y[(size_t)(r + 0) * 64 + c4] = a0;
  }
  if (r + 1 < n) {
    float s1 = dinv[r + 1];
    a1.x *= s1; a1.y *= s1; a1.z *= s1; a1.w *= s1;
    *(float4*)&Y[(size_t)(r + 1) * 64 + c4] = a1;
  }
  if (r + 2 < n) {
    float s2 = dinv[r + 2];
    a2.x *= s2; a2.y *= s2; a2.z *= s2; a2.w *= s2;
    *(float4*)&Y[(size_t)(r + 2) * 64 + c4] = a2;
  }
  if (r + 3 < n) {
    float s3 = dinv[r + 3];
    a3.x *= s3; a3.y *= s3; a3.z *= s3; a3.w *= s3;
    *(float4*)&Y[(size_t)(r + 3) * 64 + c4] = a3;
  }
}

// Aggregation: wave owns 32 consecutive dst nodes; LDS acc[32][64]; sweeps
// its src-sorted packed edge segment in rounds of 16 (one coalesced entry
// load -> readlane -> 16 gathers in flight -> LDS RMW per edge).
// POOL=0: out = relu(v), POOL=1: atomicAdd into gsum.
template <int POOL>
__global__ __launch_bounds__(256) void k_agg2(
    const float* __restrict__ Hs, const int* __restrict__ csr,
    const int* __restrict__ startArr, const float* __restrict__ dinv,
    const float* __restrict__ bias, const int* __restrict__ batch,
    float* __restrict__ outv, float* __restrict__ gsum, int n, int e) {
  __shared__ float accs[4][32 * 64];  // 32 KB / block
  int t = threadIdx.x;
  int w = t >> 6, lane = t & 63;
  int task = blockIdx.x * 4 + w;
  int nodeBase = task << 5;
  if (nodeBase >= n) return;  // wave-uniform, no later block syncs
  float* a = accs[w];
#pragma unroll 4
  for (int d = 0; d < 32; ++d) a[d * 64 + lane] = 0.f;
  int p0 = startArr[nodeBase];
  int p1 = (nodeBase + 32 < n) ? startArr[nodeBase + 32] : e;
  int c = p1 - p0;
  int sub = lane & 15;
  int qlast = p1 - 1;
  for (int rb = 0; rb < c; rb += 16) {
    int q = p0 + rb + sub;
    int pk = csr[q < qlast ? q : qlast];  // coalesced 16-wide, clamped
    int rem = c - rb;                     // wave-uniform
    int e0 = __builtin_amdgcn_readlane(pk, 0);
    int e1 = __builtin_amdgcn_readlane(pk, 1);
    int e2 = __builtin_amdgcn_readlane(pk, 2);
    int e3 = __builtin_amdgcn_readlane(pk, 3);
    int e4 = __builtin_amdgcn_readlane(pk, 4);
    int e5 = __builtin_amdgcn_readlane(pk, 5);
    int e6 = __builtin_amdgcn_readlane(pk, 6);
    int e7 = __builtin_amdgcn_readlane(pk, 7);
    int e8 = __builtin_amdgcn_readlane(pk, 8);
    int e9 = __builtin_amdgcn_readlane(pk, 9);
    int e10 = __builtin_amdgcn_readlane(pk, 10);
    int e11 = __builtin_amdgcn_readlane(pk, 11);
    int e12 = __builtin_amdgcn_readlane(pk, 12);
    int e13 = __builtin_amdgcn_readlane(pk, 13);
    int e14 = __builtin_amdgcn_readlane(pk, 14);
    int e15 = __builtin_amdgcn_readlane(pk, 15);
    float t0 = 0.f, t1 = 0.f, t2 = 0.f, t3 = 0.f;
    float t4 = 0.f, t5 = 0.f, t6 = 0.f, t7 = 0.f;
    float t8 = 0.f, t9 = 0.f, t10 = 0.f, t11 = 0.f;
    float t12 = 0.f, t13 = 0.f, t14 = 0.f, t15 = 0.f;
    {
      t0 = Hs[(size_t)(e0 >> 5) * 64 + lane];
      t1 = Hs[(size_t)(e1 >> 5) * 64 + lane];
      t2 = Hs[(size_t)(e2 >> 5) * 64 + lane];
      t3 = Hs[(size_t)(e3 >> 5) * 64 + lane];
    }
    if (rem > 4) {
      t4 = Hs[(size_t)(e4 >> 5) * 64 + lane];
      t5 = Hs[(size_t)(e5 >> 5) * 64 + lane];
      t6 = Hs[(size_t)(e6 >> 5) * 64 + lane];
      t7 = Hs[(size_t)(e7 >> 5) * 64 + lane];
    }
    if (rem > 8) {
      t8 = Hs[(size_t)(e8 >> 5) * 64 + lane];
      t9 = Hs[(size_t)(e9 >> 5) * 64 + lane];
      t10 = Hs[(size_t)(e10 >> 5) * 64 + lane];
      t11 = Hs[(size_t)(e11 >> 5) * 64 + lane];
    }
    if (rem > 12) {
      t12 = Hs[(size_t)(e12 >> 5) * 64 + lane];
      t13 = Hs[(size_t)(e13 >> 5) * 64 + lane];
      t14 = Hs[(size_t)(e14 >> 5) * 64 + lane];
      t15 = Hs[(size_t)(e15 >> 5) * 64 + lane];
    }
    // In-order wave-private LDS accumulate (no hazards; duplicates skipped).
    a[(e0 & 31) * 64 + lane] += t0;
    if (1 < rem) a[(e1 & 31) * 64 + lane] += t1;
    if (2 < rem) a[(e2 & 31) * 64 + lane] += t2;
    if (3 < rem) a[(e3 & 31) * 64 + lane] += t3;
    if (4 < rem) a[(e4 & 31) * 64 + lane] += t4;
    if (5 < rem) a[(e5 & 31) * 64 + lane] += t5;
    if (6 < rem) a[(e6 & 31) * 64 + lane] += t6;
    if (7 < rem) a[(e7 & 31) * 64 + lane] += t7;
    if (8 < rem) a[(e8 & 31) * 64 + lane] += t8;
    if (9 < rem) a[(e9 & 31) * 64 + lane] += t9;
    if (10 < rem) a[(e10 & 31) * 64 + lane] += t10;
    if (11 < rem) a[(e11 & 31) * 64 + lane] += t11;
    if (12 < rem) a[(e12 & 31) * 64 + lane] += t12;
    if (13 < rem) a[(e13 & 31) * 64 + lane] += t13;
    if (14 < rem) a[(e14 & 31) * 64 + lane] += t14;
    if (15 < rem) a[(e15 & 31) * 64 + lane] += t15;
  }
  // Epilogue: add self (pre-scaled), normalize, bias, relu/pool.
  for (int d = 0; d < 32; ++d) {
    int node = nodeBase + d;
    if (node >= n) break;
    float dn = dinv[node];
    float v = a[d * 64 + lane] + Hs[(size_t)node * 64 + lane];
    v = v * dn + bias[lane];
    if (POOL) {
      int g = batch[node];
      atomicAdd(&gsum[(size_t)g * 64 + lane], v);
    } else {
      outv[(size_t)node * 64 + lane] = fmaxf(v, 0.f);
    }
  }
}

// Head: per-graph wave: m = gsum/max(cnt,1); t = relu(m@W3+b3); out = t.W4+b4
__global__ __launch_bounds__(256) void k_head(
    const float* __restrict__ gsum, const float* __restrict__ gcnt,
    const float* __restrict__ W3, const float* __restrict__ b3,
    const float* __restrict__ W4, const float* __restrict__ b4,
    float* __restrict__ out, int ng) {
  int wid = (blockIdx.x * 256 + threadIdx.x) >> 6;
  int lane = threadIdx.x & 63;
  if (wid >= ng) return;
  float cden = fmaxf(gcnt[wid], 1.0f);
  float m = gsum[(size_t)wid * 64 + lane] / cden;
  float acc = b3[lane];
  for (int k = 0; k < 64; ++k) {
    float mk = __shfl(m, k);
    acc += mk * W3[k * 64 + lane];
  }
  acc = fmaxf(acc, 0.f);
  float r = acc * W4[lane];
  for (int off = 32; off; off >>= 1) r += __shfl_down(r, off);
  if (lane == 0) out[wid] = r + b4[0];
}

extern "C" void kernel_launch(void* const* d_in, const int* in_sizes, int n_in,
                              void* d_out, int out_size, void* d_ws, size_t ws_size,
                              hipStream_t stream) {
  const float* x = (const float*)d_in[0];
  const int* edge = (const int*)d_in[1];   // [2, E] int32
  const int* batch = (const int*)d_in[2];  // [N] int32, sorted
  const float* W1 = (const float*)d_in[3];
  const float* b1 = (const float*)d_in[4];
  const float* W2 = (const float*)d_in[5];
  const float* b2 = (const float*)d_in[6];
  const float* W3 = (const float*)d_in[7];
  const float* b3 = (const float*)d_in[8];
  const float* W4 = (const float*)d_in[9];
  const float* b4 = (const float*)d_in[10];
  float* out = (float*)d_out;

  const int n = in_sizes[0] / 64;   // 100000
  const int e = in_sizes[1] / 2;    // 1600000
  const int ng = out_size;          // 512
  const int* src = edge;
  const int* dst = edge + e;

  // Workspace layout (~59.4 MB total).
  char* ws = (char*)d_ws;
  size_t off = 0;
  auto alloc = [&](size_t bytes) -> void* {
    void* p = ws + off;
    off = (off + bytes + 255) & ~(size_t)255;
    return p;
  };
  float* A = (float*)alloc((size_t)n * 64 * 4);      // Hs (scaled gemm output)
  float* B = (float*)alloc((size_t)n * 64 * 4);      // relu'd layer-1 output
  float* dinv = (float*)alloc((size_t)n * 4);
  int* cnt = (int*)alloc((size_t)n * 4);
  int* startArr = (int*)alloc((size_t)n * 4);
  int* cursor = (int*)alloc((size_t)n * 4);
  int* bsum = (int*)alloc(1024);
  int* csr = (int*)alloc((size_t)e * 4);
  float* gsum = (float*)alloc((size_t)ng * 64 * 4);
  float* gcnt = (float*)alloc((size_t)ng * 4);

  const int nb = (n + 1023) / 1024;       // scan chunks (98)
  const int ntasks = (n + 31) / 32;       // node blocks (3125)
  const int nagg = (ntasks + 3) / 4;      // agg workgroups (782)

  int zmax = n;
  if (ng * 64 > zmax) zmax = ng * 64;
  k_zero<<<(zmax + 255) / 256, 256, 0, stream>>>(cnt, gsum, gcnt, n, ng * 64, ng);
  k_count<<<(e + 255) / 256, 256, 0, stream>>>(dst, cnt, e);
  k_scanA<<<nb, 256, 0, stream>>>(cnt, startArr, bsum, n);
  k_scanB<<<1, 256, 0, stream>>>(bsum, nb);
  k_scanC<<<(n + 255) / 256, 256, 0, stream>>>(startArr, cursor, bsum, cnt, dinv,
                                               batch, gcnt, n);
  k_place<<<(e + 255) / 256, 256, 0, stream>>>(src, dst, cursor, csr, e);
  k_bsort<<<ntasks, 256, 0, stream>>>(startArr, csr, n, e);

  // Layer 1: A = (x@W1)*dinv ; B = relu(agg(A)*dinv + b1)
  k_gemm64s<<<(n + 63) / 64, 256, 0, stream>>>(x, W1, dinv, A, n);
  k_agg2<0><<<nagg, 256, 0, stream>>>(A, csr, startArr, dinv, b1, batch, B, gsum,
                                      n, e);
  // Layer 2: A = (B@W2)*dinv ; pool(agg(A)*dinv + b2)
  k_gemm64s<<<(n + 63) / 64, 256, 0, stream>>>(B, W2, dinv, A, n);
  k_agg2<1><<<nagg, 256, 0, stream>>>(A, csr, startArr, dinv, b2, batch, B, gsum,
                                      n, e);
  // Head
  k_head<<<((size_t)ng * 64 + 255) / 256, 256, 0, stream>>>(gsum, gcnt, W3, b3, W4,
                                                            b4, out, ng);
}

// Round 6
// 521.062 us; speedup vs baseline: 1.3373x; 1.1389x over previous
//
#include <hip/hip_runtime.h>
#include <math.h>

// ---------------------------------------------------------------------------
// GCN: h1 = relu(norm_agg(x@W1)+b1); h2 = norm_agg(h1@W2)+b2;
//      g = mean_pool(h2, batch); out = relu(g@W3+b3)@W4 + b4
// norm_agg(h)[d] = (sum_{e: dst=d} h[src]*dinv[src] + h[d]*dinv[d]) * dinv[d]
// Build: count -> scan -> two-level line-dense scatter (49 buckets, then 64
// dst-blocks per bucket) -> per-block src-bin sort. Aggregation: wave owns 32
// dsts (LDS accumulators), sweeps its src-sorted segment so the collective
// read front stays L2-resident. GEMM epilogue pre-scales rows by dinv.
// ---------------------------------------------------------------------------

__global__ __launch_bounds__(256) void k_zero(int* cnt, float* gsum, float* gcnt,
                                              int n, int gsz, int ng) {
  int i = blockIdx.x * 256 + threadIdx.x;
  if (i < n) cnt[i] = 0;
  if (i < gsz) gsum[i] = 0.f;
  if (i < ng) gcnt[i] = 0.f;
}

__global__ __launch_bounds__(256) void k_count(const int* __restrict__ dst,
                                               int* __restrict__ cnt, int e) {
  int i = blockIdx.x * 256 + threadIdx.x;
  if (i < e) atomicAdd(&cnt[dst[i]], 1);
}

// Exclusive scan, level A: each block scans a 1024-element chunk.
__global__ __launch_bounds__(256) void k_scanA(const int* __restrict__ cnt,
                                               int* __restrict__ startArr,
                                               int* __restrict__ bsum, int n) {
  __shared__ int sh[256];
  int t = threadIdx.x, b = blockIdx.x;
  int base = b * 1024 + t * 4;
  int v0 = 0, v1 = 0, v2 = 0, v3 = 0;
  if (base + 3 < n) {
    int4 v = *(const int4*)&cnt[base];
    v0 = v.x; v1 = v.y; v2 = v.z; v3 = v.w;
  } else {
    if (base + 0 < n) v0 = cnt[base + 0];
    if (base + 1 < n) v1 = cnt[base + 1];
    if (base + 2 < n) v2 = cnt[base + 2];
  }
  int local = v0 + v1 + v2 + v3;
  sh[t] = local;
  __syncthreads();
  for (int off = 1; off < 256; off <<= 1) {
    int x = (t >= off) ? sh[t - off] : 0;
    __syncthreads();
    sh[t] += x;
    __syncthreads();
  }
  int excl = sh[t] - local;
  if (t == 255) bsum[b] = sh[255];
  if (base + 0 < n) startArr[base + 0] = excl;
  if (base + 1 < n) startArr[base + 1] = excl + v0;
  if (base + 2 < n) startArr[base + 2] = excl + v0 + v1;
  if (base + 3 < n) startArr[base + 3] = excl + v0 + v1 + v2;
}

// Level B: single block scans the (<=256) chunk totals, in place, exclusive.
__global__ __launch_bounds__(256) void k_scanB(int* __restrict__ bsum, int nb) {
  __shared__ int sh[256];
  int t = threadIdx.x;
  int v = (t < nb) ? bsum[t] : 0;
  sh[t] = v;
  __syncthreads();
  for (int off = 1; off < 256; off <<= 1) {
    int x = (t >= off) ? sh[t - off] : 0;
    __syncthreads();
    sh[t] += x;
    __syncthreads();
  }
  if (t < nb) bsum[t] = sh[t] - v;
}

// Level C: finalize scan; dinv = 1/sqrt(deg+1); gcnt; init block/bucket
// cursors at their segment bases.
__global__ __launch_bounds__(256) void k_scanC(int* __restrict__ startArr,
                                               const int* __restrict__ bsum,
                                               const int* __restrict__ cnt,
                                               float* __restrict__ dinv,
                                               const int* __restrict__ batch,
                                               float* __restrict__ gcnt,
                                               int* __restrict__ blockCursor,
                                               int* __restrict__ bucketCursor,
                                               int n) {
  int i = blockIdx.x * 256 + threadIdx.x;
  if (i >= n) return;
  int s = startArr[i] + bsum[i >> 10];
  startArr[i] = s;
  dinv[i] = 1.0f / sqrtf((float)(cnt[i] + 1));
  atomicAdd(&gcnt[batch[i]], 1.0f);
  if ((i & 31) == 0) blockCursor[i >> 5] = s;
  if ((i & 2047) == 0) bucketCursor[i >> 11] = s;
}

// Pass 1: bin edges into 49 coarse buckets (2048 nodes each) with range-dense
// writes. Entry = (dstLow6<<22) | (src<<5) | dstLocal.
__global__ __launch_bounds__(256) void k_p1(const int* __restrict__ src,
                                            const int* __restrict__ dst,
                                            int* __restrict__ bucketCursor,
                                            int* __restrict__ tmp, int e) {
  __shared__ int hist[64];
  __shared__ int gbase[64];
  int t = threadIdx.x;
  int base = blockIdx.x * 2048;
  if (t < 64) hist[t] = 0;
  __syncthreads();
  int ent[8], rk[8], bk[8];
#pragma unroll
  for (int k = 0; k < 8; ++k) {
    int i = base + k * 256 + t;
    bool v = i < e;
    int s = v ? src[i] : 0;
    int d = v ? dst[i] : 0;
    bk[k] = d >> 11;
    ent[k] = (((d >> 5) & 63) << 22) | (s << 5) | (d & 31);
    rk[k] = v ? atomicAdd(&hist[bk[k]], 1) : -1;
  }
  __syncthreads();
  if (t < 64 && hist[t] > 0) gbase[t] = atomicAdd(&bucketCursor[t], hist[t]);
  __syncthreads();
#pragma unroll
  for (int k = 0; k < 8; ++k)
    if (rk[k] >= 0) tmp[gbase[bk[k]] + rk[k]] = ent[k];
}

// Pass 2: within each bucket (8 slices/bucket), bin entries to their dst-block
// segment (64 bins), range-dense writes; strip top 6 bits for final csr.
__global__ __launch_bounds__(256) void k_p2(const int* __restrict__ startArr,
                                            const int* __restrict__ tmp,
                                            int* __restrict__ blockCursor,
                                            int* __restrict__ csr, int n, int e) {
  __shared__ int hist[64];
  __shared__ int gbase[64];
  int b = blockIdx.x >> 3;
  int sl = blockIdx.x & 7;
  int lo_b = startArr[b << 11];
  int hi_b = (((b + 1) << 11) < n) ? startArr[(b + 1) << 11] : e;
  int len = hi_b - lo_b;
  int lo = lo_b + (int)(((long long)len * sl) >> 3);
  int hi = lo_b + (int)(((long long)len * (sl + 1)) >> 3);
  int t = threadIdx.x;
  for (int rbase = lo; rbase < hi; rbase += 2048) {
    if (t < 64) hist[t] = 0;
    __syncthreads();
    int ent[8], rk[8], bin[8];
#pragma unroll
    for (int k = 0; k < 8; ++k) {
      int i = rbase + k * 256 + t;
      bool v = i < hi;
      int en = v ? tmp[i] : 0;
      ent[k] = en;
      bin[k] = en >> 22;
      rk[k] = v ? atomicAdd(&hist[bin[k]], 1) : -1;
    }
    __syncthreads();
    if (t < 64 && hist[t] > 0)
      gbase[t] = atomicAdd(&blockCursor[(b << 6) + t], hist[t]);
    __syncthreads();
#pragma unroll
    for (int k = 0; k < 8; ++k)
      if (rk[k] >= 0) csr[gbase[bin[k]] + rk[k]] = ent[k] & 0x3FFFFF;
    __syncthreads();
  }
}

// Per-node-block (32 dsts) counting sort of the packed edge segment by
// src>>11 (64 bins of 2048 rows). Locality-only transform.
__global__ __launch_bounds__(256) void k_bsort(const int* __restrict__ startArr,
                                               int* __restrict__ csr, int n, int e) {
  __shared__ int in_sh[1024];
  __shared__ int out_sh[1024];
  __shared__ int hist[64];
  __shared__ int hscan[64];
  int nodeBase = blockIdx.x << 5;
  if (nodeBase >= n) return;
  int p0 = startArr[nodeBase];
  int p1 = (nodeBase + 32 < n) ? startArr[nodeBase + 32] : e;
  int seg = p1 - p0;
  if (seg <= 0 || seg > 1024) return;  // block-uniform exit
  int t = threadIdx.x;
  if (t < 64) hist[t] = 0;
  __syncthreads();
  for (int i = t; i < seg; i += 256) {
    int v = csr[p0 + i];
    in_sh[i] = v;
    atomicAdd(&hist[v >> 16], 1);  // (src<<5)>>16 == src>>11
  }
  __syncthreads();
  if (t == 0) {
    int s = 0;
    for (int b = 0; b < 64; ++b) {
      hscan[b] = s;
      s += hist[b];
    }
  }
  __syncthreads();
  for (int i = t; i < seg; i += 256) {
    int v = in_sh[i];
    int pos = atomicAdd(&hscan[v >> 16], 1);
    out_sh[pos] = v;
  }
  __syncthreads();
  for (int i = t; i < seg; i += 256) csr[p0 + i] = out_sh[i];
}

// Y[N,64] = (X[N,64] @ W[64,64]) * dinv[row]  (row-scaled epilogue).
__global__ __launch_bounds__(256) void k_gemm64s(const float* __restrict__ X,
                                                 const float* __restrict__ W,
                                                 const float* __restrict__ dinv,
                                                 float* __restrict__ Y, int n) {
  __shared__ float Xs[64 * 65];
  __shared__ float Ws[64 * 64];
  int t = threadIdx.x;
  int r0 = blockIdx.x << 6;
  for (int i = t * 4; i < 4096; i += 1024)
    *(float4*)&Ws[i] = *(const float4*)&W[i];
  for (int s = t; s < 1024; s += 256) {
    int r = s >> 4, c4 = (s & 15) << 2;
    float4 v = make_float4(0.f, 0.f, 0.f, 0.f);
    if (r0 + r < n) v = *(const float4*)&X[(size_t)(r0 + r) * 64 + c4];
    Xs[r * 65 + c4 + 0] = v.x;
    Xs[r * 65 + c4 + 1] = v.y;
    Xs[r * 65 + c4 + 2] = v.z;
    Xs[r * 65 + c4 + 3] = v.w;
  }
  __syncthreads();
  int c4 = (t & 15) << 2;
  int rb = (t >> 4) << 2;
  float4 a0 = {0, 0, 0, 0}, a1 = {0, 0, 0, 0}, a2 = {0, 0, 0, 0}, a3 = {0, 0, 0, 0};
  for (int k = 0; k < 64; ++k) {
    float4 w = *(const float4*)&Ws[k * 64 + c4];
    float x0 = Xs[(rb + 0) * 65 + k];
    float x1 = Xs[(rb + 1) * 65 + k];
    float x2 = Xs[(rb + 2) * 65 + k];
    float x3 = Xs[(rb + 3) * 65 + k];
    a0.x += x0 * w.x; a0.y += x0 * w.y; a0.z += x0 * w.z; a0.w += x0 * w.w;
    a1.x += x1 * w.x; a1.y += x1 * w.y; a1.z += x1 * w.z; a1.w += x1 * w.w;
    a2.x += x2 * w.x; a2.y += x2 * w.y; a2.z += x2 * w.z; a2.w += x2 * w.w;
    a3.x += x3 * w.x; a3.y += x3 * w.y; a3.z += x3 * w.z; a3.w += x3 * w.w;
  }
  int r = r0 + rb;
  if (r + 0 < n) {
    float s0 = dinv[r + 0];
    a0.x *= s0; a0.y *= s0; a0.z *= s0; a0.w *= s0;
    *(float4*)&Y[(size_t)(r + 0) * 64 + c4] = a0;
  }
  if (r + 1 < n) {
    float s1 = dinv[r + 1];
    a1.x *= s1; a1.y *= s1; a1.z *= s1; a1.w *= s1;
    *(float4*)&Y[(size_t)(r + 1) * 64 + c4] = a1;
  }
  if (r + 2 < n) {
    float s2 = dinv[r + 2];
    a2.x *= s2; a2.y *= s2; a2.z *= s2; a2.w *= s2;
    *(float4*)&Y[(size_t)(r + 2) * 64 + c4] = a2;
  }
  if (r + 3 < n) {
    float s3 = dinv[r + 3];
    a3.x *= s3; a3.y *= s3; a3.z *= s3; a3.w *= s3;
    *(float4*)&Y[(size_t)(r + 3) * 64 + c4] = a3;
  }
}

// Aggregation: wave owns 32 consecutive dst nodes; LDS acc[32][64]; sweeps
// its src-sorted packed edge segment in rounds of 16.
// POOL=0: out = relu(v), POOL=1: atomicAdd into gsum.
template <int POOL>
__global__ __launch_bounds__(256) void k_agg2(
    const float* __restrict__ Hs, const int* __restrict__ csr,
    const int* __restrict__ startArr, const float* __restrict__ dinv,
    const float* __restrict__ bias, const int* __restrict__ batch,
    float* __restrict__ outv, float* __restrict__ gsum, int n, int e) {
  __shared__ float accs[4][32 * 64];  // 32 KB / block
  int t = threadIdx.x;
  int w = t >> 6, lane = t & 63;
  int task = blockIdx.x * 4 + w;
  int nodeBase = task << 5;
  if (nodeBase >= n) return;  // wave-uniform, no later block syncs
  float* a = accs[w];
#pragma unroll 4
  for (int d = 0; d < 32; ++d) a[d * 64 + lane] = 0.f;
  int p0 = startArr[nodeBase];
  int p1 = (nodeBase + 32 < n) ? startArr[nodeBase + 32] : e;
  int c = p1 - p0;
  int sub = lane & 15;
  int qlast = p1 - 1;
  for (int rb = 0; rb < c; rb += 16) {
    int q = p0 + rb + sub;
    int pk = csr[q < qlast ? q : qlast];  // coalesced 16-wide, clamped
    int rem = c - rb;                     // wave-uniform
    int e0 = __builtin_amdgcn_readlane(pk, 0);
    int e1 = __builtin_amdgcn_readlane(pk, 1);
    int e2 = __builtin_amdgcn_readlane(pk, 2);
    int e3 = __builtin_amdgcn_readlane(pk, 3);
    int e4 = __builtin_amdgcn_readlane(pk, 4);
    int e5 = __builtin_amdgcn_readlane(pk, 5);
    int e6 = __builtin_amdgcn_readlane(pk, 6);
    int e7 = __builtin_amdgcn_readlane(pk, 7);
    int e8 = __builtin_amdgcn_readlane(pk, 8);
    int e9 = __builtin_amdgcn_readlane(pk, 9);
    int e10 = __builtin_amdgcn_readlane(pk, 10);
    int e11 = __builtin_amdgcn_readlane(pk, 11);
    int e12 = __builtin_amdgcn_readlane(pk, 12);
    int e13 = __builtin_amdgcn_readlane(pk, 13);
    int e14 = __builtin_amdgcn_readlane(pk, 14);
    int e15 = __builtin_amdgcn_readlane(pk, 15);
    float t0 = 0.f, t1 = 0.f, t2 = 0.f, t3 = 0.f;
    float t4 = 0.f, t5 = 0.f, t6 = 0.f, t7 = 0.f;
    float t8 = 0.f, t9 = 0.f, t10 = 0.f, t11 = 0.f;
    float t12 = 0.f, t13 = 0.f, t14 = 0.f, t15 = 0.f;
    {
      t0 = Hs[(size_t)(e0 >> 5) * 64 + lane];
      t1 = Hs[(size_t)(e1 >> 5) * 64 + lane];
      t2 = Hs[(size_t)(e2 >> 5) * 64 + lane];
      t3 = Hs[(size_t)(e3 >> 5) * 64 + lane];
    }
    if (rem > 4) {
      t4 = Hs[(size_t)(e4 >> 5) * 64 + lane];
      t5 = Hs[(size_t)(e5 >> 5) * 64 + lane];
      t6 = Hs[(size_t)(e6 >> 5) * 64 + lane];
      t7 = Hs[(size_t)(e7 >> 5) * 64 + lane];
    }
    if (rem > 8) {
      t8 = Hs[(size_t)(e8 >> 5) * 64 + lane];
      t9 = Hs[(size_t)(e9 >> 5) * 64 + lane];
      t10 = Hs[(size_t)(e10 >> 5) * 64 + lane];
      t11 = Hs[(size_t)(e11 >> 5) * 64 + lane];
    }
    if (rem > 12) {
      t12 = Hs[(size_t)(e12 >> 5) * 64 + lane];
      t13 = Hs[(size_t)(e13 >> 5) * 64 + lane];
      t14 = Hs[(size_t)(e14 >> 5) * 64 + lane];
      t15 = Hs[(size_t)(e15 >> 5) * 64 + lane];
    }
    a[(e0 & 31) * 64 + lane] += t0;
    if (1 < rem) a[(e1 & 31) * 64 + lane] += t1;
    if (2 < rem) a[(e2 & 31) * 64 + lane] += t2;
    if (3 < rem) a[(e3 & 31) * 64 + lane] += t3;
    if (4 < rem) a[(e4 & 31) * 64 + lane] += t4;
    if (5 < rem) a[(e5 & 31) * 64 + lane] += t5;
    if (6 < rem) a[(e6 & 31) * 64 + lane] += t6;
    if (7 < rem) a[(e7 & 31) * 64 + lane] += t7;
    if (8 < rem) a[(e8 & 31) * 64 + lane] += t8;
    if (9 < rem) a[(e9 & 31) * 64 + lane] += t9;
    if (10 < rem) a[(e10 & 31) * 64 + lane] += t10;
    if (11 < rem) a[(e11 & 31) * 64 + lane] += t11;
    if (12 < rem) a[(e12 & 31) * 64 + lane] += t12;
    if (13 < rem) a[(e13 & 31) * 64 + lane] += t13;
    if (14 < rem) a[(e14 & 31) * 64 + lane] += t14;
    if (15 < rem) a[(e15 & 31) * 64 + lane] += t15;
  }
  for (int d = 0; d < 32; ++d) {
    int node = nodeBase + d;
    if (node >= n) break;
    float dn = dinv[node];
    float v = a[d * 64 + lane] + Hs[(size_t)node * 64 + lane];
    v = v * dn + bias[lane];
    if (POOL) {
      int g = batch[node];
      atomicAdd(&gsum[(size_t)g * 64 + lane], v);
    } else {
      outv[(size_t)node * 64 + lane] = fmaxf(v, 0.f);
    }
  }
}

// Head: per-graph wave: m = gsum/max(cnt,1); t = relu(m@W3+b3); out = t.W4+b4
__global__ __launch_bounds__(256) void k_head(
    const float* __restrict__ gsum, const float* __restrict__ gcnt,
    const float* __restrict__ W3, const float* __restrict__ b3,
    const float* __restrict__ W4, const float* __restrict__ b4,
    float* __restrict__ out, int ng) {
  int wid = (blockIdx.x * 256 + threadIdx.x) >> 6;
  int lane = threadIdx.x & 63;
  if (wid >= ng) return;
  float cden = fmaxf(gcnt[wid], 1.0f);
  float m = gsum[(size_t)wid * 64 + lane] / cden;
  float acc = b3[lane];
  for (int k = 0; k < 64; ++k) {
    float mk = __shfl(m, k);
    acc += mk * W3[k * 64 + lane];
  }
  acc = fmaxf(acc, 0.f);
  float r = acc * W4[lane];
  for (int off = 32; off; off >>= 1) r += __shfl_down(r, off);
  if (lane == 0) out[wid] = r + b4[0];
}

extern "C" void kernel_launch(void* const* d_in, const int* in_sizes, int n_in,
                              void* d_out, int out_size, void* d_ws, size_t ws_size,
                              hipStream_t stream) {
  const float* x = (const float*)d_in[0];
  const int* edge = (const int*)d_in[1];   // [2, E] int32
  const int* batch = (const int*)d_in[2];  // [N] int32, sorted
  const float* W1 = (const float*)d_in[3];
  const float* b1 = (const float*)d_in[4];
  const float* W2 = (const float*)d_in[5];
  const float* b2 = (const float*)d_in[6];
  const float* W3 = (const float*)d_in[7];
  const float* b3 = (const float*)d_in[8];
  const float* W4 = (const float*)d_in[9];
  const float* b4 = (const float*)d_in[10];
  float* out = (float*)d_out;

  const int n = in_sizes[0] / 64;   // 100000
  const int e = in_sizes[1] / 2;    // 1600000
  const int ng = out_size;          // 512
  const int* src = edge;
  const int* dst = edge + e;

  // Workspace layout (~59.4 MB total).
  char* ws = (char*)d_ws;
  size_t off = 0;
  auto alloc = [&](size_t bytes) -> void* {
    void* p = ws + off;
    off = (off + bytes + 255) & ~(size_t)255;
    return p;
  };
  float* A = (float*)alloc((size_t)n * 64 * 4);      // Hs (scaled gemm output)
  float* B = (float*)alloc((size_t)n * 64 * 4);      // relu out; tmp during build
  float* dinv = (float*)alloc((size_t)n * 4);
  int* cnt = (int*)alloc((size_t)n * 4);
  int* startArr = (int*)alloc((size_t)n * 4);
  int* blockCursor = (int*)alloc(3200 * 4);
  int* bucketCursor = (int*)alloc(64 * 4);
  int* bsum = (int*)alloc(1024);
  int* csr = (int*)alloc((size_t)e * 4);
  float* gsum = (float*)alloc((size_t)ng * 64 * 4);
  float* gcnt = (float*)alloc((size_t)ng * 4);
  int* tmp = (int*)B;  // build-time only; B not live yet

  const int nb = (n + 1023) / 1024;       // scan chunks (98)
  const int ntasks = (n + 31) / 32;       // node blocks (3125)
  const int nagg = (ntasks + 3) / 4;      // agg workgroups (782)
  const int nbuck = (ntasks + 63) / 64;   // coarse buckets (49)

  int zmax = n;
  if (ng * 64 > zmax) zmax = ng * 64;
  k_zero<<<(zmax + 255) / 256, 256, 0, stream>>>(cnt, gsum, gcnt, n, ng * 64, ng);
  k_count<<<(e + 255) / 256, 256, 0, stream>>>(dst, cnt, e);
  k_scanA<<<nb, 256, 0, stream>>>(cnt, startArr, bsum, n);
  k_scanB<<<1, 256, 0, stream>>>(bsum, nb);
  k_scanC<<<(n + 255) / 256, 256, 0, stream>>>(startArr, bsum, cnt, dinv, batch,
                                               gcnt, blockCursor, bucketCursor, n);
  k_p1<<<(e + 2047) / 2048, 256, 0, stream>>>(src, dst, bucketCursor, tmp, e);
  k_p2<<<nbuck * 8, 256, 0, stream>>>(startArr, tmp, blockCursor, csr, n, e);
  k_bsort<<<ntasks, 256, 0, stream>>>(startArr, csr, n, e);

  // Layer 1: A = (x@W1)*dinv ; B = relu(agg(A)*dinv + b1)
  k_gemm64s<<<(n + 63) / 64, 256, 0, stream>>>(x, W1, dinv, A, n);
  k_agg2<0><<<nagg, 256, 0, stream>>>(A, csr, startArr, dinv, b1, batch, B, gsum,
                                      n, e);
  // Layer 2: A = (B@W2)*dinv ; pool(agg(A)*dinv + b2)
  k_gemm64s<<<(n + 63) / 64, 256, 0, stream>>>(B, W2, dinv, A, n);
  k_agg2<1><<<nagg, 256, 0, stream>>>(A, csr, startArr, dinv, b2, batch, B, gsum,
                                      n, e);
  // Head
  k_head<<<((size_t)ng * 64 + 255) / 256, 256, 0, stream>>>(gsum, gcnt, W3, b3, W4,
                                                            b4, out, ng);
}

// Round 7
// 420.616 us; speedup vs baseline: 1.6567x; 1.2388x over previous
//
#include <hip/hip_runtime.h>
#include <math.h>

// ---------------------------------------------------------------------------
// GCN: h1 = relu(norm_agg(x@W1)+b1); h2 = norm_agg(h1@W2)+b2;
//      g = mean_pool(h2, batch); out = relu(g@W3+b3)@W4 + b4
// norm_agg(h)[d] = (sum_{e: dst=d} h[src]*dinv[src] + h[d]*dinv[d]) * dinv[d]
// Build: count -> scan -> two-level line-dense scatter (49 buckets, then 64
// dst-blocks per bucket) -> per-block src-bin sort. Aggregation: wave owns 32
// dsts (LDS accumulators), sweeps its src-sorted segment so the collective
// read front stays L2-resident. GEMM epilogue pre-scales rows by dinv.
// Graph node-counts via binary search on sorted batch (no atomics -- the
// sorted batch made same-address atomics serialize ~200 deep; R6's 105us bug).
// ---------------------------------------------------------------------------

__global__ __launch_bounds__(256) void k_zero(int* cnt, float* gsum,
                                              int n, int gsz) {
  int i = blockIdx.x * 256 + threadIdx.x;
  if (i < n) cnt[i] = 0;
  if (i < gsz) gsum[i] = 0.f;
}

__global__ __launch_bounds__(256) void k_count(const int* __restrict__ dst,
                                               int* __restrict__ cnt, int e) {
  int i = blockIdx.x * 256 + threadIdx.x;
  if (i < e) atomicAdd(&cnt[dst[i]], 1);
}

// Exclusive scan, level A: each block scans a 1024-element chunk.
__global__ __launch_bounds__(256) void k_scanA(const int* __restrict__ cnt,
                                               int* __restrict__ startArr,
                                               int* __restrict__ bsum, int n) {
  __shared__ int sh[256];
  int t = threadIdx.x, b = blockIdx.x;
  int base = b * 1024 + t * 4;
  int v0 = 0, v1 = 0, v2 = 0, v3 = 0;
  if (base + 3 < n) {
    int4 v = *(const int4*)&cnt[base];
    v0 = v.x; v1 = v.y; v2 = v.z; v3 = v.w;
  } else {
    if (base + 0 < n) v0 = cnt[base + 0];
    if (base + 1 < n) v1 = cnt[base + 1];
    if (base + 2 < n) v2 = cnt[base + 2];
  }
  int local = v0 + v1 + v2 + v3;
  sh[t] = local;
  __syncthreads();
  for (int off = 1; off < 256; off <<= 1) {
    int x = (t >= off) ? sh[t - off] : 0;
    __syncthreads();
    sh[t] += x;
    __syncthreads();
  }
  int excl = sh[t] - local;
  if (t == 255) bsum[b] = sh[255];
  if (base + 0 < n) startArr[base + 0] = excl;
  if (base + 1 < n) startArr[base + 1] = excl + v0;
  if (base + 2 < n) startArr[base + 2] = excl + v0 + v1;
  if (base + 3 < n) startArr[base + 3] = excl + v0 + v1 + v2;
}

// Level B: single block scans the (<=256) chunk totals, in place, exclusive.
__global__ __launch_bounds__(256) void k_scanB(int* __restrict__ bsum, int nb) {
  __shared__ int sh[256];
  int t = threadIdx.x;
  int v = (t < nb) ? bsum[t] : 0;
  sh[t] = v;
  __syncthreads();
  for (int off = 1; off < 256; off <<= 1) {
    int x = (t >= off) ? sh[t - off] : 0;
    __syncthreads();
    sh[t] += x;
    __syncthreads();
  }
  if (t < nb) bsum[t] = sh[t] - v;
}

// Level C: finalize scan; dinv = 1/sqrt(deg+1); init block/bucket cursors.
__global__ __launch_bounds__(256) void k_scanC(int* __restrict__ startArr,
                                               const int* __restrict__ bsum,
                                               const int* __restrict__ cnt,
                                               float* __restrict__ dinv,
                                               int* __restrict__ blockCursor,
                                               int* __restrict__ bucketCursor,
                                               int n) {
  int i = blockIdx.x * 256 + threadIdx.x;
  if (i >= n) return;
  int s = startArr[i] + bsum[i >> 10];
  startArr[i] = s;
  dinv[i] = 1.0f / sqrtf((float)(cnt[i] + 1));
  if ((i & 31) == 0) blockCursor[i >> 5] = s;
  if ((i & 2047) == 0) bucketCursor[i >> 11] = s;
}

// Pass 1: bin edges into 49 coarse buckets (2048 nodes each) with range-dense
// writes. Entry = (dstLow6<<22) | (src<<5) | dstLocal.
__global__ __launch_bounds__(256) void k_p1(const int* __restrict__ src,
                                            const int* __restrict__ dst,
                                            int* __restrict__ bucketCursor,
                                            int* __restrict__ tmp, int e) {
  __shared__ int hist[64];
  __shared__ int gbase[64];
  int t = threadIdx.x;
  int base = blockIdx.x * 2048;
  if (t < 64) hist[t] = 0;
  __syncthreads();
  int ent[8], rk[8], bk[8];
#pragma unroll
  for (int k = 0; k < 8; ++k) {
    int i = base + k * 256 + t;
    bool v = i < e;
    int s = v ? src[i] : 0;
    int d = v ? dst[i] : 0;
    bk[k] = d >> 11;
    ent[k] = (((d >> 5) & 63) << 22) | (s << 5) | (d & 31);
    rk[k] = v ? atomicAdd(&hist[bk[k]], 1) : -1;
  }
  __syncthreads();
  if (t < 64 && hist[t] > 0) gbase[t] = atomicAdd(&bucketCursor[t], hist[t]);
  __syncthreads();
#pragma unroll
  for (int k = 0; k < 8; ++k)
    if (rk[k] >= 0) tmp[gbase[bk[k]] + rk[k]] = ent[k];
}

// Pass 2: within each bucket (8 slices/bucket), bin entries to their dst-block
// segment (64 bins), range-dense writes; strip top 6 bits for final csr.
__global__ __launch_bounds__(256) void k_p2(const int* __restrict__ startArr,
                                            const int* __restrict__ tmp,
                                            int* __restrict__ blockCursor,
                                            int* __restrict__ csr, int n, int e) {
  __shared__ int hist[64];
  __shared__ int gbase[64];
  int b = blockIdx.x >> 3;
  int sl = blockIdx.x & 7;
  int lo_b = startArr[b << 11];
  int hi_b = (((b + 1) << 11) < n) ? startArr[(b + 1) << 11] : e;
  int len = hi_b - lo_b;
  int lo = lo_b + (int)(((long long)len * sl) >> 3);
  int hi = lo_b + (int)(((long long)len * (sl + 1)) >> 3);
  int t = threadIdx.x;
  for (int rbase = lo; rbase < hi; rbase += 2048) {
    if (t < 64) hist[t] = 0;
    __syncthreads();
    int ent[8], rk[8], bin[8];
#pragma unroll
    for (int k = 0; k < 8; ++k) {
      int i = rbase + k * 256 + t;
      bool v = i < hi;
      int en = v ? tmp[i] : 0;
      ent[k] = en;
      bin[k] = en >> 22;
      rk[k] = v ? atomicAdd(&hist[bin[k]], 1) : -1;
    }
    __syncthreads();
    if (t < 64 && hist[t] > 0)
      gbase[t] = atomicAdd(&blockCursor[(b << 6) + t], hist[t]);
    __syncthreads();
#pragma unroll
    for (int k = 0; k < 8; ++k)
      if (rk[k] >= 0) csr[gbase[bin[k]] + rk[k]] = ent[k] & 0x3FFFFF;
    __syncthreads();
  }
}

// Per-node-block (32 dsts) counting sort of the packed edge segment by
// src>>11 (64 bins of 2048 rows). Locality-only transform.
__global__ __launch_bounds__(256) void k_bsort(const int* __restrict__ startArr,
                                               int* __restrict__ csr, int n, int e) {
  __shared__ int in_sh[1024];
  __shared__ int out_sh[1024];
  __shared__ int hist[64];
  __shared__ int hscan[64];
  int nodeBase = blockIdx.x << 5;
  if (nodeBase >= n) return;
  int p0 = startArr[nodeBase];
  int p1 = (nodeBase + 32 < n) ? startArr[nodeBase + 32] : e;
  int seg = p1 - p0;
  if (seg <= 0 || seg > 1024) return;  // block-uniform exit
  int t = threadIdx.x;
  if (t < 64) hist[t] = 0;
  __syncthreads();
  for (int i = t; i < seg; i += 256) {
    int v = csr[p0 + i];
    in_sh[i] = v;
    atomicAdd(&hist[v >> 16], 1);  // (src<<5)>>16 == src>>11
  }
  __syncthreads();
  if (t == 0) {
    int s = 0;
    for (int b = 0; b < 64; ++b) {
      hscan[b] = s;
      s += hist[b];
    }
  }
  __syncthreads();
  for (int i = t; i < seg; i += 256) {
    int v = in_sh[i];
    int pos = atomicAdd(&hscan[v >> 16], 1);
    out_sh[pos] = v;
  }
  __syncthreads();
  for (int i = t; i < seg; i += 256) csr[p0 + i] = out_sh[i];
}

// Y[N,64] = (X[N,64] @ W[64,64]) * dinv[row]  (row-scaled epilogue).
__global__ __launch_bounds__(256) void k_gemm64s(const float* __restrict__ X,
                                                 const float* __restrict__ W,
                                                 const float* __restrict__ dinv,
                                                 float* __restrict__ Y, int n) {
  __shared__ float Xs[64 * 65];
  __shared__ float Ws[64 * 64];
  int t = threadIdx.x;
  int r0 = blockIdx.x << 6;
  for (int i = t * 4; i < 4096; i += 1024)
    *(float4*)&Ws[i] = *(const float4*)&W[i];
  for (int s = t; s < 1024; s += 256) {
    int r = s >> 4, c4 = (s & 15) << 2;
    float4 v = make_float4(0.f, 0.f, 0.f, 0.f);
    if (r0 + r < n) v = *(const float4*)&X[(size_t)(r0 + r) * 64 + c4];
    Xs[r * 65 + c4 + 0] = v.x;
    Xs[r * 65 + c4 + 1] = v.y;
    Xs[r * 65 + c4 + 2] = v.z;
    Xs[r * 65 + c4 + 3] = v.w;
  }
  __syncthreads();
  int c4 = (t & 15) << 2;
  int rb = (t >> 4) << 2;
  float4 a0 = {0, 0, 0, 0}, a1 = {0, 0, 0, 0}, a2 = {0, 0, 0, 0}, a3 = {0, 0, 0, 0};
  for (int k = 0; k < 64; ++k) {
    float4 w = *(const float4*)&Ws[k * 64 + c4];
    float x0 = Xs[(rb + 0) * 65 + k];
    float x1 = Xs[(rb + 1) * 65 + k];
    float x2 = Xs[(rb + 2) * 65 + k];
    float x3 = Xs[(rb + 3) * 65 + k];
    a0.x += x0 * w.x; a0.y += x0 * w.y; a0.z += x0 * w.z; a0.w += x0 * w.w;
    a1.x += x1 * w.x; a1.y += x1 * w.y; a1.z += x1 * w.z; a1.w += x1 * w.w;
    a2.x += x2 * w.x; a2.y += x2 * w.y; a2.z += x2 * w.z; a2.w += x2 * w.w;
    a3.x += x3 * w.x; a3.y += x3 * w.y; a3.z += x3 * w.z; a3.w += x3 * w.w;
  }
  int r = r0 + rb;
  if (r + 0 < n) {
    float s0 = dinv[r + 0];
    a0.x *= s0; a0.y *= s0; a0.z *= s0; a0.w *= s0;
    *(float4*)&Y[(size_t)(r + 0) * 64 + c4] = a0;
  }
  if (r + 1 < n) {
    float s1 = dinv[r + 1];
    a1.x *= s1; a1.y *= s1; a1.z *= s1; a1.w *= s1;
    *(float4*)&Y[(size_t)(r + 1) * 64 + c4] = a1;
  }
  if (r + 2 < n) {
    float s2 = dinv[r + 2];
    a2.x *= s2; a2.y *= s2; a2.z *= s2; a2.w *= s2;
    *(float4*)&Y[(size_t)(r + 2) * 64 + c4] = a2;
  }
  if (r + 3 < n) {
    float s3 = dinv[r + 3];
    a3.x *= s3; a3.y *= s3; a3.z *= s3; a3.w *= s3;
    *(float4*)&Y[(size_t)(r + 3) * 64 + c4] = a3;
  }
}

// Aggregation: wave owns 32 consecutive dst nodes; LDS acc[32][64]; sweeps
// its src-sorted packed edge segment in rounds of 16.
// POOL=0: out = relu(v), POOL=1: atomicAdd into gsum.
template <int POOL>
__global__ __launch_bounds__(256) void k_agg2(
    const float* __restrict__ Hs, const int* __restrict__ csr,
    const int* __restrict__ startArr, const float* __restrict__ dinv,
    const float* __restrict__ bias, const int* __restrict__ batch,
    float* __restrict__ outv, float* __restrict__ gsum, int n, int e) {
  __shared__ float accs[4][32 * 64];  // 32 KB / block
  int t = threadIdx.x;
  int w = t >> 6, lane = t & 63;
  int task = blockIdx.x * 4 + w;
  int nodeBase = task << 5;
  if (nodeBase >= n) return;  // wave-uniform, no later block syncs
  float* a = accs[w];
#pragma unroll 4
  for (int d = 0; d < 32; ++d) a[d * 64 + lane] = 0.f;
  int p0 = startArr[nodeBase];
  int p1 = (nodeBase + 32 < n) ? startArr[nodeBase + 32] : e;
  int c = p1 - p0;
  int sub = lane & 15;
  int qlast = p1 - 1;
  for (int rb = 0; rb < c; rb += 16) {
    int q = p0 + rb + sub;
    int pk = csr[q < qlast ? q : qlast];  // coalesced 16-wide, clamped
    int rem = c - rb;                     // wave-uniform
    int e0 = __builtin_amdgcn_readlane(pk, 0);
    int e1 = __builtin_amdgcn_readlane(pk, 1);
    int e2 = __builtin_amdgcn_readlane(pk, 2);
    int e3 = __builtin_amdgcn_readlane(pk, 3);
    int e4 = __builtin_amdgcn_readlane(pk, 4);
    int e5 = __builtin_amdgcn_readlane(pk, 5);
    int e6 = __builtin_amdgcn_readlane(pk, 6);
    int e7 = __builtin_amdgcn_readlane(pk, 7);
    int e8 = __builtin_amdgcn_readlane(pk, 8);
    int e9 = __builtin_amdgcn_readlane(pk, 9);
    int e10 = __builtin_amdgcn_readlane(pk, 10);
    int e11 = __builtin_amdgcn_readlane(pk, 11);
    int e12 = __builtin_amdgcn_readlane(pk, 12);
    int e13 = __builtin_amdgcn_readlane(pk, 13);
    int e14 = __builtin_amdgcn_readlane(pk, 14);
    int e15 = __builtin_amdgcn_readlane(pk, 15);
    float t0 = 0.f, t1 = 0.f, t2 = 0.f, t3 = 0.f;
    float t4 = 0.f, t5 = 0.f, t6 = 0.f, t7 = 0.f;
    float t8 = 0.f, t9 = 0.f, t10 = 0.f, t11 = 0.f;
    float t12 = 0.f, t13 = 0.f, t14 = 0.f, t15 = 0.f;
    {
      t0 = Hs[(size_t)(e0 >> 5) * 64 + lane];
      t1 = Hs[(size_t)(e1 >> 5) * 64 + lane];
      t2 = Hs[(size_t)(e2 >> 5) * 64 + lane];
      t3 = Hs[(size_t)(e3 >> 5) * 64 + lane];
    }
    if (rem > 4) {
      t4 = Hs[(size_t)(e4 >> 5) * 64 + lane];
      t5 = Hs[(size_t)(e5 >> 5) * 64 + lane];
      t6 = Hs[(size_t)(e6 >> 5) * 64 + lane];
      t7 = Hs[(size_t)(e7 >> 5) * 64 + lane];
    }
    if (rem > 8) {
      t8 = Hs[(size_t)(e8 >> 5) * 64 + lane];
      t9 = Hs[(size_t)(e9 >> 5) * 64 + lane];
      t10 = Hs[(size_t)(e10 >> 5) * 64 + lane];
      t11 = Hs[(size_t)(e11 >> 5) * 64 + lane];
    }
    if (rem > 12) {
      t12 = Hs[(size_t)(e12 >> 5) * 64 + lane];
      t13 = Hs[(size_t)(e13 >> 5) * 64 + lane];
      t14 = Hs[(size_t)(e14 >> 5) * 64 + lane];
      t15 = Hs[(size_t)(e15 >> 5) * 64 + lane];
    }
    a[(e0 & 31) * 64 + lane] += t0;
    if (1 < rem) a[(e1 & 31) * 64 + lane] += t1;
    if (2 < rem) a[(e2 & 31) * 64 + lane] += t2;
    if (3 < rem) a[(e3 & 31) * 64 + lane] += t3;
    if (4 < rem) a[(e4 & 31) * 64 + lane] += t4;
    if (5 < rem) a[(e5 & 31) * 64 + lane] += t5;
    if (6 < rem) a[(e6 & 31) * 64 + lane] += t6;
    if (7 < rem) a[(e7 & 31) * 64 + lane] += t7;
    if (8 < rem) a[(e8 & 31) * 64 + lane] += t8;
    if (9 < rem) a[(e9 & 31) * 64 + lane] += t9;
    if (10 < rem) a[(e10 & 31) * 64 + lane] += t10;
    if (11 < rem) a[(e11 & 31) * 64 + lane] += t11;
    if (12 < rem) a[(e12 & 31) * 64 + lane] += t12;
    if (13 < rem) a[(e13 & 31) * 64 + lane] += t13;
    if (14 < rem) a[(e14 & 31) * 64 + lane] += t14;
    if (15 < rem) a[(e15 & 31) * 64 + lane] += t15;
  }
  for (int d = 0; d < 32; ++d) {
    int node = nodeBase + d;
    if (node >= n) break;
    float dn = dinv[node];
    float v = a[d * 64 + lane] + Hs[(size_t)node * 64 + lane];
    v = v * dn + bias[lane];
    if (POOL) {
      int g = batch[node];
      atomicAdd(&gsum[(size_t)g * 64 + lane], v);
    } else {
      outv[(size_t)node * 64 + lane] = fmaxf(v, 0.f);
    }
  }
}

// Head: per-graph wave. Node count per graph via binary search on sorted
// batch (no atomics). m = gsum/max(cnt,1); t = relu(m@W3+b3); out = t.W4+b4.
__global__ __launch_bounds__(256) void k_head(
    const float* __restrict__ gsum, const int* __restrict__ batch,
    const float* __restrict__ W3, const float* __restrict__ b3,
    const float* __restrict__ W4, const float* __restrict__ b4,
    float* __restrict__ out, int ng, int n) {
  int wid = (blockIdx.x * 256 + threadIdx.x) >> 6;
  int lane = threadIdx.x & 63;
  if (wid >= ng) return;
  // lower bound: first i with batch[i] >= wid
  int lo = 0, hi = n;
  while (lo < hi) {
    int mid = (lo + hi) >> 1;
    if (batch[mid] < wid) lo = mid + 1; else hi = mid;
  }
  int lb = lo;
  // upper bound: first i with batch[i] > wid
  hi = n;
  while (lo < hi) {
    int mid = (lo + hi) >> 1;
    if (batch[mid] <= wid) lo = mid + 1; else hi = mid;
  }
  float cden = fmaxf((float)(lo - lb), 1.0f);
  float m = gsum[(size_t)wid * 64 + lane] / cden;
  float acc = b3[lane];
  for (int k = 0; k < 64; ++k) {
    float mk = __shfl(m, k);
    acc += mk * W3[k * 64 + lane];
  }
  acc = fmaxf(acc, 0.f);
  float r = acc * W4[lane];
  for (int off = 32; off; off >>= 1) r += __shfl_down(r, off);
  if (lane == 0) out[wid] = r + b4[0];
}

extern "C" void kernel_launch(void* const* d_in, const int* in_sizes, int n_in,
                              void* d_out, int out_size, void* d_ws, size_t ws_size,
                              hipStream_t stream) {
  const float* x = (const float*)d_in[0];
  const int* edge = (const int*)d_in[1];   // [2, E] int32
  const int* batch = (const int*)d_in[2];  // [N] int32, sorted
  const float* W1 = (const float*)d_in[3];
  const float* b1 = (const float*)d_in[4];
  const float* W2 = (const float*)d_in[5];
  const float* b2 = (const float*)d_in[6];
  const float* W3 = (const float*)d_in[7];
  const float* b3 = (const float*)d_in[8];
  const float* W4 = (const float*)d_in[9];
  const float* b4 = (const float*)d_in[10];
  float* out = (float*)d_out;

  const int n = in_sizes[0] / 64;   // 100000
  const int e = in_sizes[1] / 2;    // 1600000
  const int ng = out_size;          // 512
  const int* src = edge;
  const int* dst = edge + e;

  // Workspace layout (~59.4 MB total).
  char* ws = (char*)d_ws;
  size_t off = 0;
  auto alloc = [&](size_t bytes) -> void* {
    void* p = ws + off;
    off = (off + bytes + 255) & ~(size_t)255;
    return p;
  };
  float* A = (float*)alloc((size_t)n * 64 * 4);      // Hs (scaled gemm output)
  float* B = (float*)alloc((size_t)n * 64 * 4);      // relu out; tmp during build
  float* dinv = (float*)alloc((size_t)n * 4);
  int* cnt = (int*)alloc((size_t)n * 4);
  int* startArr = (int*)alloc((size_t)n * 4);
  int* blockCursor = (int*)alloc(3200 * 4);
  int* bucketCursor = (int*)alloc(64 * 4);
  int* bsum = (int*)alloc(1024);
  int* csr = (int*)alloc((size_t)e * 4);
  float* gsum = (float*)alloc((size_t)ng * 64 * 4);
  int* tmp = (int*)B;  // build-time only; B not live yet

  const int nb = (n + 1023) / 1024;       // scan chunks (98)
  const int ntasks = (n + 31) / 32;       // node blocks (3125)
  const int nagg = (ntasks + 3) / 4;      // agg workgroups (782)
  const int nbuck = (ntasks + 63) / 64;   // coarse buckets (49)

  int zmax = n;
  if (ng * 64 > zmax) zmax = ng * 64;
  k_zero<<<(zmax + 255) / 256, 256, 0, stream>>>(cnt, gsum, n, ng * 64);
  k_count<<<(e + 255) / 256, 256, 0, stream>>>(dst, cnt, e);
  k_scanA<<<nb, 256, 0, stream>>>(cnt, startArr, bsum, n);
  k_scanB<<<1, 256, 0, stream>>>(bsum, nb);
  k_scanC<<<(n + 255) / 256, 256, 0, stream>>>(startArr, bsum, cnt, dinv,
                                               blockCursor, bucketCursor, n);
  k_p1<<<(e + 2047) / 2048, 256, 0, stream>>>(src, dst, bucketCursor, tmp, e);
  k_p2<<<nbuck * 8, 256, 0, stream>>>(startArr, tmp, blockCursor, csr, n, e);
  k_bsort<<<ntasks, 256, 0, stream>>>(startArr, csr, n, e);

  // Layer 1: A = (x@W1)*dinv ; B = relu(agg(A)*dinv + b1)
  k_gemm64s<<<(n + 63) / 64, 256, 0, stream>>>(x, W1, dinv, A, n);
  k_agg2<0><<<nagg, 256, 0, stream>>>(A, csr, startArr, dinv, b1, batch, B, gsum,
                                      n, e);
  // Layer 2: A = (B@W2)*dinv ; pool(agg(A)*dinv + b2)
  k_gemm64s<<<(n + 63) / 64, 256, 0, stream>>>(B, W2, dinv, A, n);
  k_agg2<1><<<nagg, 256, 0, stream>>>(A, csr, startArr, dinv, b2, batch, B, gsum,
                                      n, e);
  // Head
  k_head<<<((size_t)ng * 64 + 255) / 256, 256, 0, stream>>>(gsum, batch, W3, b3,
                                                            W4, b4, out, ng, n);
}